// Round 19
// baseline (2870.316 us; speedup 1.0000x reference)
//
#include <hip/hip_runtime.h>
#include <hip/hip_bf16.h>

#define BB_ 16
#define T_ 2048
#define DIN_ 64
#define D_ 512
#define DI_ 1024
#define N_ 16
#define DC_ 4
#define R_ 32
#define L_ 3
#define DOUT_ 128
#define CL_ 64               // scan chunk length
#define NCH_ (T_ / CL_)      // 32 chunks

typedef __attribute__((ext_vector_type(8))) _Float16 f16x8;
typedef __attribute__((ext_vector_type(4))) float f32x4;

__device__ __forceinline__ float silu_f(float x) { return x / (1.f + __expf(-x)); }

// fast branch-free softplus: log(1+e^t) = max(t,0) + log(1+e^-|t|)
__device__ __forceinline__ float softplus_f(float t) {
    return fmaxf(t, 0.f) + __logf(1.f + __expf(-fabsf(t)));
}

__device__ __forceinline__ unsigned short f2h(float f) {
    union { _Float16 h; unsigned short u; } c;
    c.h = (_Float16)f;   // RNE
    return c.u;
}

__device__ __forceinline__ float h2f(unsigned short u) {
    union { unsigned short u; _Float16 h; } c;
    c.u = u;
    return (float)c.h;
}

// async global->LDS 16B per lane; LDS dest must be lane-linear (tid*16B).
__device__ __forceinline__ void gload_lds16(const unsigned short* g,
                                            unsigned short* l) {
    __builtin_amdgcn_global_load_lds(
        (const __attribute__((address_space(1))) void*)g,
        (__attribute__((address_space(3))) void*)l, 16, 0, 0);
}

// decode scale from amax bits: s = 2^(11 - e), so s*amax lands in [2^11, 2^12)
__device__ __forceinline__ float decode_scale(unsigned int bits) {
    if (bits == 0u) return 1.f;
    const int E = (int)(bits >> 23) & 0xFF;
    return __uint_as_float((unsigned)(265 - E) << 23);
}

__device__ __forceinline__ uint4 pack8(float4 lo, float4 hi, float s) {
    union { uint4 u; unsigned short h[8]; } r;
    r.h[0] = f2h(lo.x * s); r.h[1] = f2h(lo.y * s);
    r.h[2] = f2h(lo.z * s); r.h[3] = f2h(lo.w * s);
    r.h[4] = f2h(hi.x * s); r.h[5] = f2h(hi.y * s);
    r.h[6] = f2h(hi.z * s); r.h[7] = f2h(hi.w * s);
    return r.u;
}

// regions: 0-2 Win[l] (262144 f4), 3-5 Wout[l] (131072), 6 Wo (16384),
// 7-9 Wx[l] (16384). slot == region.
__device__ __forceinline__ const float* wregion(
    int r, const float* Win, const float* Wout, const float* Wx,
    const float* Wo, size_t* n4)
{
    if (r < 3)       { *n4 = 262144; return Win  + (size_t)r * 1048576; }
    else if (r < 6)  { *n4 = 131072; return Wout + (size_t)(r - 3) * 524288; }
    else if (r == 6) { *n4 = 16384;  return Wo; }
    else             { *n4 = 16384;  return Wx  + (size_t)(r - 7) * 65536; }
}

__global__ __launch_bounds__(256) void amax_all(
    const float* __restrict__ Win, const float* __restrict__ Wout,
    const float* __restrict__ Wx, const float* __restrict__ Wo,
    unsigned int* __restrict__ scales)
{
    size_t n4;
    const float* p = wregion(blockIdx.z, Win, Wout, Wx, Wo, &n4);
    float m = 0.f;
    for (size_t i = (size_t)blockIdx.x * 256 + threadIdx.x; i < n4;
         i += (size_t)gridDim.x * 256) {
        const float4 v = ((const float4*)p)[i];
        m = fmaxf(m, fmaxf(fmaxf(fabsf(v.x), fabsf(v.y)),
                           fmaxf(fabsf(v.z), fabsf(v.w))));
    }
#pragma unroll
    for (int off = 32; off; off >>= 1) m = fmaxf(m, __shfl_down(m, off));
    __shared__ float sm[4];
    if ((threadIdx.x & 63) == 0) sm[threadIdx.x >> 6] = m;
    __syncthreads();
    if (threadIdx.x == 0) {
        const float b = fmaxf(fmaxf(sm[0], sm[1]), fmaxf(sm[2], sm[3]));
        atomicMax(scales + blockIdx.z, __float_as_uint(b));
    }
}

__global__ __launch_bounds__(256) void cast_all(
    const float* __restrict__ Win, const float* __restrict__ Wout,
    const float* __restrict__ Wx, const float* __restrict__ Wo,
    unsigned short* __restrict__ WinH, unsigned short* __restrict__ WoutH,
    unsigned short* __restrict__ WxH, unsigned short* __restrict__ WoH,
    const unsigned int* __restrict__ scales)
{
    const int r = blockIdx.z;
    size_t n4;
    const float* p = wregion(r, Win, Wout, Wx, Wo, &n4);
    unsigned short* o;
    if (r < 3)       o = WinH  + (size_t)r * 1048576;
    else if (r < 6)  o = WoutH + (size_t)(r - 3) * 524288;
    else if (r == 6) o = WoH;
    else             o = WxH   + (size_t)(r - 7) * 65536;
    const float s = decode_scale(scales[r]);
    for (size_t i = (size_t)blockIdx.x * 256 + threadIdx.x; i < n4;
         i += (size_t)gridDim.x * 256) {
        const float4 v = ((const float4*)p)[i];
        ((ushort4*)o)[i] = make_ushort4(f2h(v.x * s), f2h(v.y * s),
                                        f2h(v.z * s), f2h(v.w * s));
    }
}

// tiny: u amax upper bound = max_c(|cb|+Sum|w|*amax_xz). 1 block.
__global__ __launch_bounds__(256) void ubound_kernel(
    const float* __restrict__ cw, const float* __restrict__ cb,
    const unsigned int* __restrict__ xzslot, unsigned int* __restrict__ uslot)
{
    const float amx = __uint_as_float(*xzslot);
    float m = 0.f;
    for (int c = threadIdx.x; c < DI_; c += 256) {
        const float4 w = *(const float4*)(cw + (size_t)c * 4);
        const float sw = fabsf(w.x) + fabsf(w.y) + fabsf(w.z) + fabsf(w.w);
        m = fmaxf(m, fabsf(cb[c]) + sw * amx);
    }
#pragma unroll
    for (int off = 32; off; off >>= 1) m = fmaxf(m, __shfl_down(m, off));
    __shared__ float sm[4];
    if ((threadIdx.x & 63) == 0) sm[threadIdx.x >> 6] = m;
    __syncthreads();
    if (threadIdx.x == 0) {
        const float b = fmaxf(fmaxf(sm[0], sm[1]), fmaxf(sm[2], sm[3]));
        atomicMax(uslot, __float_as_uint(b));
    }
}

// ------- scaled MFMA GEMM, A fp32 (cast during LDS staging), B f16 --------
// 128x128 tile, BK=32, 4 waves (2x2), per-wave 64x64 = 4x4 frags of 16x16x32.
// A: reg-prefetch pipeline. B: async global_load_lds, double-buffered.
// ACT: 0 = none, 3 = +bias tanh. Output fp32 (+ optional amax).
// NOTE: C must NOT alias A.
template<int ACT>
__global__ __launch_bounds__(256) void gemm_f32a_t128(
    const float* __restrict__ A, int lda,
    const unsigned short* __restrict__ B, int ldb,
    const float* __restrict__ bias,
    float* __restrict__ C, int ldc, int K,
    const unsigned int* __restrict__ sa, const unsigned int* __restrict__ sb,
    unsigned int* __restrict__ oamax)
{
    __shared__ __align__(16) unsigned short As[128 * 32];
    __shared__ __align__(16) unsigned short Bs[2][128 * 32];
    const int tid  = threadIdx.x;
    const int lane = tid & 63;
    const int w    = tid >> 6;
    const int wr   = (w >> 1) << 6;
    const int wc   = (w & 1) << 6;
    const int l15  = lane & 15, l4 = lane >> 4;
    const int row0 = blockIdx.y << 7, col0 = blockIdx.x << 7;
    const int tq   = tid >> 2;
    const int tr   = (tid & 3) << 3;

    const float sA  = decode_scale(*sa);
    const float inv = (1.f / sA) * (1.f / decode_scale(*sb));

    const float* Ar0 = A + (size_t)(row0 + tq) * lda + tr;
    const float* Ar1 = A + (size_t)(row0 + 64 + tq) * lda + tr;
    const unsigned short* Br0 = B + (size_t)(col0 + tq) * ldb + tr;
    const unsigned short* Br1 = B + (size_t)(col0 + 64 + tq) * ldb + tr;

    f32x4 acc[4][4];
#pragma unroll
    for (int m = 0; m < 4; ++m)
#pragma unroll
        for (int n = 0; n < 4; ++n) acc[m][n] = (f32x4){0.f, 0.f, 0.f, 0.f};

    float4 a0lo = *(const float4*)(Ar0), a0hi = *(const float4*)(Ar0 + 4);
    float4 a1lo = *(const float4*)(Ar1), a1hi = *(const float4*)(Ar1 + 4);
    gload_lds16(Br0, &Bs[0][tq * 32 + tr]);
    gload_lds16(Br1, &Bs[0][(64 + tq) * 32 + tr]);

    int cur = 0;
    for (int k0 = 0; k0 < K; k0 += 32) {
        __syncthreads();
        *(uint4*)&As[tq * 32 + tr]        = pack8(a0lo, a0hi, sA);
        *(uint4*)&As[(64 + tq) * 32 + tr] = pack8(a1lo, a1hi, sA);
        __syncthreads();

        if (k0 + 32 < K) {
            gload_lds16(Br0 + k0 + 32, &Bs[cur ^ 1][tq * 32 + tr]);
            gload_lds16(Br1 + k0 + 32, &Bs[cur ^ 1][(64 + tq) * 32 + tr]);
            a0lo = *(const float4*)(Ar0 + k0 + 32);
            a0hi = *(const float4*)(Ar0 + k0 + 36);
            a1lo = *(const float4*)(Ar1 + k0 + 32);
            a1hi = *(const float4*)(Ar1 + k0 + 36);
        }

        f16x8 af[4], bfr[4];
#pragma unroll
        for (int m = 0; m < 4; ++m)
            af[m] = *(const f16x8*)&As[(wr + m * 16 + l15) * 32 + l4 * 8];
#pragma unroll
        for (int n = 0; n < 4; ++n)
            bfr[n] = *(const f16x8*)&Bs[cur][(wc + n * 16 + l15) * 32 + l4 * 8];
#pragma unroll
        for (int m = 0; m < 4; ++m)
#pragma unroll
            for (int n = 0; n < 4; ++n)
                acc[m][n] = __builtin_amdgcn_mfma_f32_16x16x32_f16(
                    af[m], bfr[n], acc[m][n], 0, 0, 0);
        cur ^= 1;
    }

    float am = 0.f;
#pragma unroll
    for (int n = 0; n < 4; ++n) {
        const int col = col0 + wc + n * 16 + l15;
        float bc = 0.f;
        if (ACT == 3) bc = bias[col];
#pragma unroll
        for (int m = 0; m < 4; ++m) {
            const int rowb = row0 + wr + m * 16 + (l4 << 2);
#pragma unroll
            for (int r = 0; r < 4; ++r) {
                float v = acc[m][n][r] * inv;
                if (ACT == 3) v = tanhf(v + bc);
                C[(size_t)(rowb + r) * ldc + col] = v;
                am = fmaxf(am, fabsf(v));
            }
        }
    }
    if (oamax) {
#pragma unroll
        for (int off = 32; off; off >>= 1) am = fmaxf(am, __shfl_down(am, off));
        if (lane == 0) atomicMax(oamax, __float_as_uint(am));
    }
}

// ---- dbc GEMM: A f16 u (already scaled), B f16 Wx. 128x64 tile, pipelined.
__global__ __launch_bounds__(256) void gemm_f16_t64n(
    const unsigned short* __restrict__ A, int lda,
    const unsigned short* __restrict__ B, int ldb,
    float* __restrict__ C, int ldc, int K,
    const unsigned int* __restrict__ sa, const unsigned int* __restrict__ sb)
{
    __shared__ __align__(16) unsigned short As[128 * 32];
    __shared__ __align__(16) unsigned short Bs[64 * 32];
    const int tid  = threadIdx.x;
    const int lane = tid & 63;
    const int w    = tid >> 6;
    const int l15  = lane & 15, l4 = lane >> 4;
    const int row0 = blockIdx.y << 7;
    const int tq   = tid >> 2;
    const int tr   = (tid & 3) << 3;

    const float inv = (1.f / decode_scale(*sa)) * (1.f / decode_scale(*sb));

    const unsigned short* Ar0 = A + (size_t)(row0 + tq) * lda + tr;
    const unsigned short* Ar1 = A + (size_t)(row0 + 64 + tq) * lda + tr;
    const unsigned short* Br  = B + (size_t)tq * ldb + tr;   // 64 rows

    f32x4 acc[2][4];
#pragma unroll
    for (int m = 0; m < 2; ++m)
#pragma unroll
        for (int n = 0; n < 4; ++n) acc[m][n] = (f32x4){0.f, 0.f, 0.f, 0.f};

    uint4 av0 = *(const uint4*)(Ar0);
    uint4 av1 = *(const uint4*)(Ar1);
    uint4 bv  = *(const uint4*)(Br);

    for (int k0 = 0; k0 < K; k0 += 32) {
        __syncthreads();
        *(uint4*)&As[tq * 32 + tr]        = av0;
        *(uint4*)&As[(64 + tq) * 32 + tr] = av1;
        *(uint4*)&Bs[tq * 32 + tr]        = bv;
        __syncthreads();

        if (k0 + 32 < K) {
            av0 = *(const uint4*)(Ar0 + k0 + 32);
            av1 = *(const uint4*)(Ar1 + k0 + 32);
            bv  = *(const uint4*)(Br  + k0 + 32);
        }

        f16x8 af[2], bfr[4];
#pragma unroll
        for (int m = 0; m < 2; ++m)
            af[m] = *(const f16x8*)&As[(w * 32 + m * 16 + l15) * 32 + l4 * 8];
#pragma unroll
        for (int n = 0; n < 4; ++n)
            bfr[n] = *(const f16x8*)&Bs[(n * 16 + l15) * 32 + l4 * 8];
#pragma unroll
        for (int m = 0; m < 2; ++m)
#pragma unroll
            for (int n = 0; n < 4; ++n)
                acc[m][n] = __builtin_amdgcn_mfma_f32_16x16x32_f16(
                    af[m], bfr[n], acc[m][n], 0, 0, 0);
    }

#pragma unroll
    for (int n = 0; n < 4; ++n) {
        const int col = n * 16 + l15;
#pragma unroll
        for (int m = 0; m < 2; ++m) {
            const int rowb = row0 + w * 32 + m * 16 + (l4 << 2);
#pragma unroll
            for (int r = 0; r < 4; ++r)
                C[(size_t)(rowb + r) * ldc + col] = acc[m][n][r] * inv;
        }
    }
}

// ---------------- fp32 vector GEMM (input projection, K=64) ----------------
__global__ __launch_bounds__(256) void gemm_in(
    const float* __restrict__ A, int lda,
    const float* __restrict__ B, int ldb,
    const float* __restrict__ bias,
    float* __restrict__ C, int ldc, int K,
    unsigned int* __restrict__ oamax)
{
    __shared__ __align__(16) float As[8][128];
    __shared__ __align__(16) float Bs[8][128];
    const int tid  = threadIdx.x;
    const int row0 = blockIdx.y << 7;
    const int col0 = blockIdx.x << 7;
    const int tx = tid & 15, ty = tid >> 4;

    float acc[8][8];
#pragma unroll
    for (int i = 0; i < 8; ++i)
#pragma unroll
        for (int j = 0; j < 8; ++j) acc[i][j] = 0.f;

    const int arow = tid >> 1;
    const int acol = (tid & 1) << 2;
    const float* Ap = A + (size_t)(row0 + arow) * lda + acol;
    const float* Bp = B + (size_t)(col0 + arow) * ldb + acol;

    for (int k0 = 0; k0 < K; k0 += 8) {
        const float4 av = *(const float4*)(Ap + k0);
        const float4 bv = *(const float4*)(Bp + k0);
        __syncthreads();
        As[acol + 0][arow] = av.x; As[acol + 1][arow] = av.y;
        As[acol + 2][arow] = av.z; As[acol + 3][arow] = av.w;
        Bs[acol + 0][arow] = bv.x; Bs[acol + 1][arow] = bv.y;
        Bs[acol + 2][arow] = bv.z; Bs[acol + 3][arow] = bv.w;
        __syncthreads();
#pragma unroll
        for (int k = 0; k < 8; ++k) {
            float a[8], b[8];
            *(float4*)&a[0] = *(const float4*)&As[k][ty << 3];
            *(float4*)&a[4] = *(const float4*)&As[k][(ty << 3) + 4];
            *(float4*)&b[0] = *(const float4*)&Bs[k][tx << 3];
            *(float4*)&b[4] = *(const float4*)&Bs[k][(tx << 3) + 4];
#pragma unroll
            for (int i = 0; i < 8; ++i)
#pragma unroll
                for (int j = 0; j < 8; ++j)
                    acc[i][j] = fmaf(a[i], b[j], acc[i][j]);
        }
    }

    float bv8[8];
#pragma unroll
    for (int j = 0; j < 8; ++j) bv8[j] = bias[col0 + (tx << 3) + j];

    float am = 0.f;
#pragma unroll
    for (int i = 0; i < 8; ++i) {
        float v[8];
#pragma unroll
        for (int j = 0; j < 8; ++j) {
            v[j] = acc[i][j] + bv8[j];
            am = fmaxf(am, fabsf(v[j]));
        }
        float* Cp = C + (size_t)(row0 + (ty << 3) + i) * ldc + col0 + (tx << 3);
        *(float4*)(Cp)     = make_float4(v[0], v[1], v[2], v[3]);
        *(float4*)(Cp + 4) = make_float4(v[4], v[5], v[6], v[7]);
    }
#pragma unroll
    for (int off = 32; off; off >>= 1) am = fmaxf(am, __shfl_down(am, off));
    if ((tid & 63) == 0) atomicMax(oamax, __float_as_uint(am));
}

// depthwise causal conv (DC=4) + bias + SiLU, float4 in / scaled f16 out.
__global__ __launch_bounds__(256) void conv_silu_kernel(
    const float* __restrict__ xz, const float* __restrict__ cw,
    const float* __restrict__ cb, unsigned short* __restrict__ u,
    size_t total4, const unsigned int* __restrict__ uslot)
{
    const float s = decode_scale(*uslot);
    for (size_t i = (size_t)blockIdx.x * 256 + threadIdx.x; i < total4;
         i += (size_t)gridDim.x * 256) {
        const size_t e = i * 4;
        const int c = (int)(e & (DI_ - 1));
        const size_t m = e >> 10;
        const int t = (int)(m & (T_ - 1));
        const float* xr = xz + m * 2048 + c;
        const float4 zero = make_float4(0.f, 0.f, 0.f, 0.f);
        const float4 x0 = (t >= 3) ? *(const float4*)(xr - 3 * 2048) : zero;
        const float4 x1 = (t >= 2) ? *(const float4*)(xr - 2 * 2048) : zero;
        const float4 x2 = (t >= 1) ? *(const float4*)(xr - 1 * 2048) : zero;
        const float4 x3 = *(const float4*)(xr);
        const float4 cbv = *(const float4*)(cb + c);
        const float4 w0 = *(const float4*)(cw + (size_t)c * 4);
        const float4 w1 = *(const float4*)(cw + (size_t)(c + 1) * 4);
        const float4 w2 = *(const float4*)(cw + (size_t)(c + 2) * 4);
        const float4 w3 = *(const float4*)(cw + (size_t)(c + 3) * 4);
        float4 r;
        r.x = silu_f(fmaf(x3.x, w0.w, fmaf(x2.x, w0.z, fmaf(x1.x, w0.y, fmaf(x0.x, w0.x, cbv.x)))));
        r.y = silu_f(fmaf(x3.y, w1.w, fmaf(x2.y, w1.z, fmaf(x1.y, w1.y, fmaf(x0.y, w1.x, cbv.y)))));
        r.z = silu_f(fmaf(x3.z, w2.w, fmaf(x2.z, w2.z, fmaf(x1.z, w2.y, fmaf(x0.z, w2.x, cbv.z)))));
        r.w = silu_f(fmaf(x3.w, w3.w, fmaf(x2.w, w3.z, fmaf(x1.w, w3.y, fmaf(x0.w, w3.x, cbv.w)))));
        *(ushort4*)(u + e) = make_ushort4(f2h(r.x * s), f2h(r.y * s),
                                          f2h(r.z * s), f2h(r.w * s));
    }
}

// -------- chunk-parallel selective scan, delta fused (3 phases) -----------
// u stored f16 (scale 1/sU applied on load). delta inline from dbc+Wdt.
// Carry state compressed: pass1 stores sdl = Sum(dl); carry reconstructs p.

__device__ __forceinline__ bool geo_check(const float* a2) {
    bool ok = true;
#pragma unroll
    for (int n = 1; n < N_; ++n)
        ok = ok && (fabsf(a2[n] - a2[0] * (n + 1)) <=
                    1e-5f * fmaxf(1.f, fabsf(a2[n])));
    return ok;
}

__global__ __launch_bounds__(256) void scan_pass1(
    const unsigned short* __restrict__ u, const float* __restrict__ dbc,
    const float* __restrict__ A_log_l, const float* __restrict__ Wdt_l,
    const float* __restrict__ bdt_l, const unsigned int* __restrict__ uslot,
    float* __restrict__ SDL, float* __restrict__ S)
{
    __shared__ __align__(16) float sAll[CL_][64];
    const int tid = threadIdx.x;
    const int b = blockIdx.x, ch = blockIdx.z;
    const int d = (blockIdx.y << 8) + tid;

    float a2[N_], hs[N_];
#pragma unroll
    for (int n = 0; n < N_; ++n) {
        a2[n] = -__expf(A_log_l[d * N_ + n]) * 1.44269504f;
        hs[n] = 0.f;
    }
    const bool geo = geo_check(a2);
    const float invU = 1.f / decode_scale(*uslot);
    float wdt[32];
#pragma unroll
    for (int k = 0; k < 32; k += 4)
        *(float4*)&wdt[k] = *(const float4*)(Wdt_l + (size_t)d * 32 + k);
    const float bdt_d = bdt_l[d];

    const size_t base64 = ((size_t)b * T_ + (size_t)ch * CL_) * 64;
    float* sflat = &sAll[0][0];
    for (int i = tid; i < CL_ * 64; i += 256) sflat[i] = dbc[base64 + i];
    __syncthreads();

    float sdl = 0.f;
    if (geo) {
        for (int tt = 0; tt < CL_; ++tt) {
            float t = bdt_d;
#pragma unroll
            for (int k = 0; k < 32; k += 4) {
                const float4 dv = *(const float4*)&sAll[tt][k];
                t = fmaf(dv.x, wdt[k + 0], t);
                t = fmaf(dv.y, wdt[k + 1], t);
                t = fmaf(dv.z, wdt[k + 2], t);
                t = fmaf(dv.w, wdt[k + 3], t);
            }
            const float dl = softplus_f(t);
            sdl += dl;
            const size_t m = (size_t)b * T_ + ch * CL_ + tt;
            const float du = dl * (h2f(u[m * DI_ + d]) * invU);
            const float r = exp2f(dl * a2[0]);
            float dA = r;
#pragma unroll
            for (int n = 0; n < N_; ++n) {
                hs[n] = fmaf(dA, hs[n], du * sAll[tt][32 + n]);
                dA *= r;
            }
        }
    } else {
        for (int tt = 0; tt < CL_; ++tt) {
            float t = bdt_d;
#pragma unroll
            for (int k = 0; k < 32; k += 4) {
                const float4 dv = *(const float4*)&sAll[tt][k];
                t = fmaf(dv.x, wdt[k + 0], t);
                t = fmaf(dv.y, wdt[k + 1], t);
                t = fmaf(dv.z, wdt[k + 2], t);
                t = fmaf(dv.w, wdt[k + 3], t);
            }
            const float dl = softplus_f(t);
            sdl += dl;
            const size_t m = (size_t)b * T_ + ch * CL_ + tt;
            const float du = dl * (h2f(u[m * DI_ + d]) * invU);
#pragma unroll
            for (int n = 0; n < N_; ++n) {
                const float dA = exp2f(dl * a2[n]);
                hs[n] = fmaf(dA, hs[n], du * sAll[tt][32 + n]);
            }
        }
    }
    SDL[(size_t)((b * NCH_ + ch) << 10) + d] = sdl;
#pragma unroll
    for (int n = 0; n < N_; ++n) {
        const size_t idx = (size_t)(((b * NCH_ + ch) * N_ + n) << 10) + d;
        S[idx] = hs[n];
    }
}

// carry: per (b,n,d); p reconstructed from sdl. S[ch] becomes h_init(ch).
__global__ __launch_bounds__(256) void scan_carry(
    const float* __restrict__ SDL, float* __restrict__ S,
    const float* __restrict__ A_log_l)
{
    const size_t gid = (size_t)blockIdx.x * 256 + threadIdx.x;
    const int d = (int)(gid & 1023);
    const int n = (int)((gid >> 10) & 15);
    const int b = (int)(gid >> 14);
    const float a2n = -__expf(A_log_l[d * N_ + n]) * 1.44269504f;
    float hc = 0.f;
    for (int ch = 0; ch < NCH_; ++ch) {
        const float sdl = SDL[(size_t)((b * NCH_ + ch) << 10) + d];
        const float p = exp2f(sdl * a2n);
        const size_t idx = (size_t)(((b * NCH_ + ch) * N_ + n) << 10) + d;
        const float s = S[idx];
        S[idx] = hc;
        hc = fmaf(p, hc, s);
    }
}

__global__ __launch_bounds__(256) void scan_pass3(
    float* __restrict__ xz, const unsigned short* __restrict__ u,
    const float* __restrict__ dbc, const float* __restrict__ A_log_l,
    const float* __restrict__ Wdt_l, const float* __restrict__ bdt_l,
    const float* __restrict__ Dp_l, const unsigned int* __restrict__ uslot,
    const float* __restrict__ S, unsigned int* __restrict__ gmax)
{
    __shared__ __align__(16) float sAll[CL_][64];
    const int tid = threadIdx.x;
    const int b = blockIdx.x, ch = blockIdx.z;
    const int d = (blockIdx.y << 8) + tid;

    float a2[N_], hs[N_];
#pragma unroll
    for (int n = 0; n < N_; ++n) {
        a2[n] = -__expf(A_log_l[d * N_ + n]) * 1.44269504f;
        hs[n] = S[(size_t)(((b * NCH_ + ch) * N_ + n) << 10) + d];
    }
    const bool geo = geo_check(a2);
    const float invU = 1.f / decode_scale(*uslot);
    float wdt[32];
#pragma unroll
    for (int k = 0; k < 32; k += 4)
        *(float4*)&wdt[k] = *(const float4*)(Wdt_l + (size_t)d * 32 + k);
    const float bdt_d = bdt_l[d];
    const float Dpd = Dp_l[d];

    const size_t base64 = ((size_t)b * T_ + (size_t)ch * CL_) * 64;
    float* sflat = &sAll[0][0];
    for (int i = tid; i < CL_ * 64; i += 256) sflat[i] = dbc[base64 + i];
    __syncthreads();

    float gm = 0.f;
    if (geo) {
        for (int tt = 0; tt < CL_; ++tt) {
            float t = bdt_d;
#pragma unroll
            for (int k = 0; k < 32; k += 4) {
                const float4 dv = *(const float4*)&sAll[tt][k];
                t = fmaf(dv.x, wdt[k + 0], t);
                t = fmaf(dv.y, wdt[k + 1], t);
                t = fmaf(dv.z, wdt[k + 2], t);
                t = fmaf(dv.w, wdt[k + 3], t);
            }
            const float dl = softplus_f(t);
            const size_t m = (size_t)b * T_ + ch * CL_ + tt;
            const float uv = h2f(u[m * DI_ + d]) * invU;
            const float du = dl * uv;
            const float r = exp2f(dl * a2[0]);
            float dA = r;
            float yv = 0.f;
#pragma unroll
            for (int n = 0; n < N_; ++n) {
                hs[n] = fmaf(dA, hs[n], du * sAll[tt][32 + n]);
                yv = fmaf(hs[n], sAll[tt][48 + n], yv);
                dA *= r;
            }
            yv = fmaf(uv, Dpd, yv);
            const float g = yv * silu_f(xz[m * 2048 + DI_ + d]);
            xz[m * 2048 + d] = g;
            gm = fmaxf(gm, fabsf(g));
        }
    } else {
        for (int tt = 0; tt < CL_; ++tt) {
            float t = bdt_d;
#pragma unroll
            for (int k = 0; k < 32; k += 4) {
                const float4 dv = *(const float4*)&sAll[tt][k];
                t = fmaf(dv.x, wdt[k + 0], t);
                t = fmaf(dv.y, wdt[k + 1], t);
                t = fmaf(dv.z, wdt[k + 2], t);
                t = fmaf(dv.w, wdt[k + 3], t);
            }
            const float dl = softplus_f(t);
            const size_t m = (size_t)b * T_ + ch * CL_ + tt;
            const float uv = h2f(u[m * DI_ + d]) * invU;
            const float du = dl * uv;
            float yv = 0.f;
#pragma unroll
            for (int n = 0; n < N_; ++n) {
                const float dA = exp2f(dl * a2[n]);
                hs[n] = fmaf(dA, hs[n], du * sAll[tt][32 + n]);
                yv = fmaf(hs[n], sAll[tt][48 + n], yv);
            }
            yv = fmaf(uv, Dpd, yv);
            const float g = yv * silu_f(xz[m * 2048 + DI_ + d]);
            xz[m * 2048 + d] = g;
            gm = fmaxf(gm, fabsf(g));
        }
    }
#pragma unroll
    for (int off = 32; off; off >>= 1) gm = fmaxf(gm, __shfl_down(gm, off));
    if ((tid & 63) == 0) atomicMax(gmax, __float_as_uint(gm));
}

extern "C" void kernel_launch(void* const* d_in, const int* in_sizes, int n_in,
                              void* d_out, int out_size, void* d_ws, size_t ws_size,
                              hipStream_t stream) {
    const float* x     = (const float*)d_in[0];
    const float* Wi    = (const float*)d_in[1];
    const float* bi    = (const float*)d_in[2];
    const float* Win   = (const float*)d_in[3];
    const float* convw = (const float*)d_in[4];
    const float* convb = (const float*)d_in[5];
    const float* Wx    = (const float*)d_in[6];
    const float* Wdt   = (const float*)d_in[7];
    const float* bdt   = (const float*)d_in[8];
    const float* A_log = (const float*)d_in[9];
    const float* Dp    = (const float*)d_in[10];
    const float* Wout  = (const float*)d_in[11];
    const float* Wo    = (const float*)d_in[12];
    const float* bo    = (const float*)d_in[13];
    float* out = (float*)d_out;

    // Per-row f32: xz 2048 + u(f16) 512 + dbc 64 + hPS 512 (h | SDL+S) = 3136.
    // (Keep the proven 3648 budget check for safety margin.)
    const size_t rowf = 3648;
    const size_t wextra =
        (3 * 1048576 + 3 * 524288 + 65536 + 3 * 65536) / 2 + 32;
    int CB = BB_;
    while (CB > 1 && ((size_t)CB * T_ * rowf + wextra) * sizeof(float) > ws_size) CB >>= 1;
    const size_t Mc = (size_t)CB * T_;

    const dim3 blk(256);
    const int rowTiles = (int)(Mc / 128);

    float* ws   = (float*)d_ws;
    float* xz   = ws;                    // Mc*2048 (xin/g | z)
    float* uf   = xz + Mc * 2048;        // Mc*512 f32 = Mc*1024 ushorts (u f16)
    unsigned short* ub = (unsigned short*)uf;
    float* dbc  = uf + Mc * 512;         // Mc*64
    float* hPS  = dbc + Mc * 64;         // Mc*512: h (ld 512) / SDL+S
    float* hb   = hPS;
    float* Sdl  = hPS;                               // Mc*16 floats
    float* Sbuf = hPS + Mc * 16;                     // Mc*256 floats
    unsigned short* WinH  = (unsigned short*)(hPS + Mc * 512);
    unsigned short* WoutH = WinH + 3 * 1048576;
    unsigned short* WoH   = WoutH + 3 * 524288;
    unsigned short* WxH   = WoH + 65536;
    unsigned int* scales  = (unsigned int*)(WxH + 3 * 65536);
    // slots: 0-2 Win, 3-5 Wout, 6 Wo, 7-9 Wx,
    //        10..13 h[0..3], 14-16 g[l], 17-19 xzamax[l], 20-22 ubound[l]

    hipMemsetAsync(scales, 0, 32 * sizeof(unsigned int), stream);

    amax_all<<<dim3(128, 1, 10), blk, 0, stream>>>(Win, Wout, Wx, Wo, scales);
    cast_all<<<dim3(64, 1, 10), blk, 0, stream>>>(
        Win, Wout, Wx, Wo, WinH, WoutH, WxH, WoH, scales);

    for (int c = 0; c < BB_ / CB; ++c) {
        const float* x_c = x + (size_t)c * Mc * DIN_;
        float* out_c     = out + (size_t)c * Mc * DOUT_;

        hipMemsetAsync(scales + 10, 0, 16 * sizeof(unsigned int), stream);

        // h = x @ Wi.T + bi  (fp32, K=64) -> hb (ld 512), amax -> h[0]
        gemm_in<<<dim3(D_ / 128, rowTiles), blk, 0, stream>>>(
            x_c, DIN_, Wi, DIN_, bi, hb, D_, DIN_, scales + 10);

        for (int l = 0; l < L_; ++l) {
            const float* cw_l   = convw + (size_t)l * DI_ * DC_;
            const float* cb_l   = convb + (size_t)l * DI_;
            const float* Wdt_l  = Wdt  + (size_t)l * DI_ * R_;
            const float* bdt_l  = bdt  + (size_t)l * DI_;
            const float* Alog_l = A_log + (size_t)l * DI_ * N_;
            const float* Dp_l   = Dp   + (size_t)l * DI_;

            // xz = h @ Win.T  (A fp32 staged-cast, B async-lds); amax(xz)
            gemm_f32a_t128<0><<<dim3(2048 / 128, rowTiles), blk, 0, stream>>>(
                hb, D_, WinH + (size_t)l * 1048576, D_, nullptr,
                xz, 2048, D_, scales + 10 + l, scales + l, scales + 17 + l);

            // u-scale bound from amax(xz) and conv weights (tiny)
            ubound_kernel<<<dim3(1), blk, 0, stream>>>(
                cw_l, cb_l, scales + 17 + l, scales + 20 + l);

            // u(f16) = silu(causal_dwconv(xin) + cb) * sU
            conv_silu_kernel<<<dim3(2048), blk, 0, stream>>>(
                xz, cw_l, cb_l, ub, Mc * DI_ / 4, scales + 20 + l);

            // dbc = u @ Wx.T  (f16 MFMA 128x64, A pre-scaled f16)
            gemm_f16_t64n<<<dim3(1, rowTiles), blk, 0, stream>>>(
                ub, DI_, WxH + (size_t)l * 65536, DI_, dbc, 64, DI_,
                scales + 20 + l, scales + 7 + l);

            // chunk-parallel scan with fused delta; g -> xz[:, :1024]
            scan_pass1<<<dim3(CB, DI_ / 256, NCH_), blk, 0, stream>>>(
                ub, dbc, Alog_l, Wdt_l, bdt_l, scales + 20 + l, Sdl, Sbuf);
            scan_carry<<<dim3(CB * 64), blk, 0, stream>>>(Sdl, Sbuf, Alog_l);
            scan_pass3<<<dim3(CB, DI_ / 256, NCH_), blk, 0, stream>>>(
                xz, ub, dbc, Alog_l, Wdt_l, bdt_l, Dp_l, scales + 20 + l,
                Sbuf, scales + 14 + l);

            // h = g @ Wout.T  (A fp32 staged-cast) -> hb (SDL/S dead)
            gemm_f32a_t128<0><<<dim3(D_ / 128, rowTiles), blk, 0, stream>>>(
                xz, 2048, WoutH + (size_t)l * 524288, DI_, nullptr,
                hb, D_, DI_, scales + 14 + l, scales + 3 + l, scales + 11 + l);
        }

        // out = tanh(h @ Wo.T + bo)
        gemm_f32a_t128<3><<<dim3(DOUT_ / 128, rowTiles), blk, 0, stream>>>(
            hb, D_, WoH, D_, bo, out_c, DOUT_, D_,
            scales + 13, scales + 6, nullptr);
    }
}

// Round 20
// 2582.240 us; speedup vs baseline: 1.1116x; 1.1116x over previous
//
#include <hip/hip_runtime.h>
#include <hip/hip_bf16.h>

#define BB_ 16
#define T_ 2048
#define DIN_ 64
#define D_ 512
#define DI_ 1024
#define N_ 16
#define DC_ 4
#define R_ 32
#define L_ 3
#define DOUT_ 128
#define CL_ 64               // scan chunk length
#define NCH_ (T_ / CL_)      // 32 chunks

typedef __attribute__((ext_vector_type(8))) _Float16 f16x8;
typedef __attribute__((ext_vector_type(4))) float f32x4;

__device__ __forceinline__ float silu_f(float x) { return x / (1.f + __expf(-x)); }

// fast branch-free softplus: log(1+e^t) = max(t,0) + log(1+e^-|t|)
__device__ __forceinline__ float softplus_f(float t) {
    return fmaxf(t, 0.f) + __logf(1.f + __expf(-fabsf(t)));
}

__device__ __forceinline__ unsigned short f2h(float f) {
    union { _Float16 h; unsigned short u; } c;
    c.h = (_Float16)f;   // RNE
    return c.u;
}

__device__ __forceinline__ float h2f(unsigned short u) {
    union { unsigned short u; _Float16 h; } c;
    c.u = u;
    return (float)c.h;
}

// async global->LDS 16B per lane; LDS dest must be lane-linear (tid*16B).
__device__ __forceinline__ void gload_lds16(const unsigned short* g,
                                            unsigned short* l) {
    __builtin_amdgcn_global_load_lds(
        (const __attribute__((address_space(1))) void*)g,
        (__attribute__((address_space(3))) void*)l, 16, 0, 0);
}

// decode scale from amax bits: s = 2^(11 - e), so s*amax lands in [2^11, 2^12)
__device__ __forceinline__ float decode_scale(unsigned int bits) {
    if (bits == 0u) return 1.f;
    const int E = (int)(bits >> 23) & 0xFF;
    return __uint_as_float((unsigned)(265 - E) << 23);
}

__device__ __forceinline__ uint4 pack8(float4 lo, float4 hi, float s) {
    union { uint4 u; unsigned short h[8]; } r;
    r.h[0] = f2h(lo.x * s); r.h[1] = f2h(lo.y * s);
    r.h[2] = f2h(lo.z * s); r.h[3] = f2h(lo.w * s);
    r.h[4] = f2h(hi.x * s); r.h[5] = f2h(hi.y * s);
    r.h[6] = f2h(hi.z * s); r.h[7] = f2h(hi.w * s);
    return r.u;
}

// regions: 0-2 Win[l] (262144 f4), 3-5 Wout[l] (131072), 6 Wo (16384),
// 7-9 Wx[l] (16384). slot == region.
__device__ __forceinline__ const float* wregion(
    int r, const float* Win, const float* Wout, const float* Wx,
    const float* Wo, size_t* n4)
{
    if (r < 3)       { *n4 = 262144; return Win  + (size_t)r * 1048576; }
    else if (r < 6)  { *n4 = 131072; return Wout + (size_t)(r - 3) * 524288; }
    else if (r == 6) { *n4 = 16384;  return Wo; }
    else             { *n4 = 16384;  return Wx  + (size_t)(r - 7) * 65536; }
}

__global__ __launch_bounds__(256) void amax_all(
    const float* __restrict__ Win, const float* __restrict__ Wout,
    const float* __restrict__ Wx, const float* __restrict__ Wo,
    unsigned int* __restrict__ scales)
{
    size_t n4;
    const float* p = wregion(blockIdx.z, Win, Wout, Wx, Wo, &n4);
    float m = 0.f;
    for (size_t i = (size_t)blockIdx.x * 256 + threadIdx.x; i < n4;
         i += (size_t)gridDim.x * 256) {
        const float4 v = ((const float4*)p)[i];
        m = fmaxf(m, fmaxf(fmaxf(fabsf(v.x), fabsf(v.y)),
                           fmaxf(fabsf(v.z), fabsf(v.w))));
    }
#pragma unroll
    for (int off = 32; off; off >>= 1) m = fmaxf(m, __shfl_down(m, off));
    __shared__ float sm[4];
    if ((threadIdx.x & 63) == 0) sm[threadIdx.x >> 6] = m;
    __syncthreads();
    if (threadIdx.x == 0) {
        const float b = fmaxf(fmaxf(sm[0], sm[1]), fmaxf(sm[2], sm[3]));
        atomicMax(scales + blockIdx.z, __float_as_uint(b));
    }
}

__global__ __launch_bounds__(256) void cast_all(
    const float* __restrict__ Win, const float* __restrict__ Wout,
    const float* __restrict__ Wx, const float* __restrict__ Wo,
    unsigned short* __restrict__ WinH, unsigned short* __restrict__ WoutH,
    unsigned short* __restrict__ WxH, unsigned short* __restrict__ WoH,
    const unsigned int* __restrict__ scales)
{
    const int r = blockIdx.z;
    size_t n4;
    const float* p = wregion(r, Win, Wout, Wx, Wo, &n4);
    unsigned short* o;
    if (r < 3)       o = WinH  + (size_t)r * 1048576;
    else if (r < 6)  o = WoutH + (size_t)(r - 3) * 524288;
    else if (r == 6) o = WoH;
    else             o = WxH   + (size_t)(r - 7) * 65536;
    const float s = decode_scale(scales[r]);
    for (size_t i = (size_t)blockIdx.x * 256 + threadIdx.x; i < n4;
         i += (size_t)gridDim.x * 256) {
        const float4 v = ((const float4*)p)[i];
        ((ushort4*)o)[i] = make_ushort4(f2h(v.x * s), f2h(v.y * s),
                                        f2h(v.z * s), f2h(v.w * s));
    }
}

// weight prep: wb[l] = max_j Sum_k |Win[l][j][k]|  -> scales[26+l].
// grid (512, 1, 3): 4 rows/block, 64 lanes/row, 8 cols/lane.
__global__ __launch_bounds__(256) void winrow_kernel(
    const float* __restrict__ Win, unsigned int* __restrict__ scales)
{
    const int l = blockIdx.z;
    const int row = blockIdx.x * 4 + (threadIdx.x >> 6);
    const int lane = threadIdx.x & 63;
    const float* W = Win + (size_t)l * 2 * DI_ * D_ + (size_t)row * D_ + lane * 8;
    float s = 0.f;
#pragma unroll
    for (int k = 0; k < 8; k += 4) {
        const float4 v = *(const float4*)(W + k);
        s += fabsf(v.x) + fabsf(v.y) + fabsf(v.z) + fabsf(v.w);
    }
#pragma unroll
    for (int off = 32; off; off >>= 1) s += __shfl_down(s, off);
    if (lane == 0) atomicMax(scales + 26 + l, __float_as_uint(s));
}

// tiny: u amax upper bound from amax(h)*wb and conv weights. 1 block.
__global__ __launch_bounds__(256) void ubound_kernel(
    const float* __restrict__ cw, const float* __restrict__ cb,
    const unsigned int* __restrict__ hslot,
    const unsigned int* __restrict__ wbslot,
    unsigned int* __restrict__ uslot)
{
    const float amx = __uint_as_float(*hslot) * __uint_as_float(*wbslot);
    float m = 0.f;
    for (int c = threadIdx.x; c < DI_; c += 256) {
        const float4 w = *(const float4*)(cw + (size_t)c * 4);
        const float sw = fabsf(w.x) + fabsf(w.y) + fabsf(w.z) + fabsf(w.w);
        m = fmaxf(m, fabsf(cb[c]) + sw * amx);
    }
#pragma unroll
    for (int off = 32; off; off >>= 1) m = fmaxf(m, __shfl_down(m, off));
    __shared__ float sm[4];
    if ((threadIdx.x & 63) == 0) sm[threadIdx.x >> 6] = m;
    __syncthreads();
    if (threadIdx.x == 0) {
        const float b = fmaxf(fmaxf(sm[0], sm[1]), fmaxf(sm[2], sm[3]));
        atomicMax(uslot, __float_as_uint(b));
    }
}

// ------- scaled MFMA GEMM, A fp32 (cast during LDS staging), B f16 --------
// 128x128 tile, BK=32, 4 waves (2x2), per-wave 64x64 = 4x4 frags of 16x16x32.
// A: reg-prefetch pipeline. B: async global_load_lds, double-buffered.
// ACT: 0 = none, 3 = +bias tanh. Output fp32 (+ optional amax).
// NOTE: C must NOT alias A.
template<int ACT>
__global__ __launch_bounds__(256) void gemm_f32a_t128(
    const float* __restrict__ A, int lda,
    const unsigned short* __restrict__ B, int ldb,
    const float* __restrict__ bias,
    float* __restrict__ C, int ldc, int K,
    const unsigned int* __restrict__ sa, const unsigned int* __restrict__ sb,
    unsigned int* __restrict__ oamax)
{
    __shared__ __align__(16) unsigned short As[128 * 32];
    __shared__ __align__(16) unsigned short Bs[2][128 * 32];
    const int tid  = threadIdx.x;
    const int lane = tid & 63;
    const int w    = tid >> 6;
    const int wr   = (w >> 1) << 6;
    const int wc   = (w & 1) << 6;
    const int l15  = lane & 15, l4 = lane >> 4;
    const int row0 = blockIdx.y << 7, col0 = blockIdx.x << 7;
    const int tq   = tid >> 2;
    const int tr   = (tid & 3) << 3;

    const float sA  = decode_scale(*sa);
    const float inv = (1.f / sA) * (1.f / decode_scale(*sb));

    const float* Ar0 = A + (size_t)(row0 + tq) * lda + tr;
    const float* Ar1 = A + (size_t)(row0 + 64 + tq) * lda + tr;
    const unsigned short* Br0 = B + (size_t)(col0 + tq) * ldb + tr;
    const unsigned short* Br1 = B + (size_t)(col0 + 64 + tq) * ldb + tr;

    f32x4 acc[4][4];
#pragma unroll
    for (int m = 0; m < 4; ++m)
#pragma unroll
        for (int n = 0; n < 4; ++n) acc[m][n] = (f32x4){0.f, 0.f, 0.f, 0.f};

    float4 a0lo = *(const float4*)(Ar0), a0hi = *(const float4*)(Ar0 + 4);
    float4 a1lo = *(const float4*)(Ar1), a1hi = *(const float4*)(Ar1 + 4);
    gload_lds16(Br0, &Bs[0][tq * 32 + tr]);
    gload_lds16(Br1, &Bs[0][(64 + tq) * 32 + tr]);

    int cur = 0;
    for (int k0 = 0; k0 < K; k0 += 32) {
        __syncthreads();
        *(uint4*)&As[tq * 32 + tr]        = pack8(a0lo, a0hi, sA);
        *(uint4*)&As[(64 + tq) * 32 + tr] = pack8(a1lo, a1hi, sA);
        __syncthreads();

        if (k0 + 32 < K) {
            gload_lds16(Br0 + k0 + 32, &Bs[cur ^ 1][tq * 32 + tr]);
            gload_lds16(Br1 + k0 + 32, &Bs[cur ^ 1][(64 + tq) * 32 + tr]);
            a0lo = *(const float4*)(Ar0 + k0 + 32);
            a0hi = *(const float4*)(Ar0 + k0 + 36);
            a1lo = *(const float4*)(Ar1 + k0 + 32);
            a1hi = *(const float4*)(Ar1 + k0 + 36);
        }

        f16x8 af[4], bfr[4];
#pragma unroll
        for (int m = 0; m < 4; ++m)
            af[m] = *(const f16x8*)&As[(wr + m * 16 + l15) * 32 + l4 * 8];
#pragma unroll
        for (int n = 0; n < 4; ++n)
            bfr[n] = *(const f16x8*)&Bs[cur][(wc + n * 16 + l15) * 32 + l4 * 8];
#pragma unroll
        for (int m = 0; m < 4; ++m)
#pragma unroll
            for (int n = 0; n < 4; ++n)
                acc[m][n] = __builtin_amdgcn_mfma_f32_16x16x32_f16(
                    af[m], bfr[n], acc[m][n], 0, 0, 0);
        cur ^= 1;
    }

    float am = 0.f;
#pragma unroll
    for (int n = 0; n < 4; ++n) {
        const int col = col0 + wc + n * 16 + l15;
        float bc = 0.f;
        if (ACT == 3) bc = bias[col];
#pragma unroll
        for (int m = 0; m < 4; ++m) {
            const int rowb = row0 + wr + m * 16 + (l4 << 2);
#pragma unroll
            for (int r = 0; r < 4; ++r) {
                float v = acc[m][n][r] * inv;
                if (ACT == 3) v = tanhf(v + bc);
                C[(size_t)(rowb + r) * ldc + col] = v;
                am = fmaxf(am, fabsf(v));
            }
        }
    }
    if (oamax) {
#pragma unroll
        for (int off = 32; off; off >>= 1) am = fmaxf(am, __shfl_down(am, off));
        if (lane == 0) atomicMax(oamax, __float_as_uint(am));
    }
}

// ---- dbc GEMM: A f16 u (already scaled), B f16 Wx. 128x64 tile, pipelined.
__global__ __launch_bounds__(256) void gemm_f16_t64n(
    const unsigned short* __restrict__ A, int lda,
    const unsigned short* __restrict__ B, int ldb,
    float* __restrict__ C, int ldc, int K,
    const unsigned int* __restrict__ sa, const unsigned int* __restrict__ sb)
{
    __shared__ __align__(16) unsigned short As[128 * 32];
    __shared__ __align__(16) unsigned short Bs[64 * 32];
    const int tid  = threadIdx.x;
    const int lane = tid & 63;
    const int w    = tid >> 6;
    const int l15  = lane & 15, l4 = lane >> 4;
    const int row0 = blockIdx.y << 7;
    const int tq   = tid >> 2;
    const int tr   = (tid & 3) << 3;

    const float inv = (1.f / decode_scale(*sa)) * (1.f / decode_scale(*sb));

    const unsigned short* Ar0 = A + (size_t)(row0 + tq) * lda + tr;
    const unsigned short* Ar1 = A + (size_t)(row0 + 64 + tq) * lda + tr;
    const unsigned short* Br  = B + (size_t)tq * ldb + tr;   // 64 rows

    f32x4 acc[2][4];
#pragma unroll
    for (int m = 0; m < 2; ++m)
#pragma unroll
        for (int n = 0; n < 4; ++n) acc[m][n] = (f32x4){0.f, 0.f, 0.f, 0.f};

    uint4 av0 = *(const uint4*)(Ar0);
    uint4 av1 = *(const uint4*)(Ar1);
    uint4 bv  = *(const uint4*)(Br);

    for (int k0 = 0; k0 < K; k0 += 32) {
        __syncthreads();
        *(uint4*)&As[tq * 32 + tr]        = av0;
        *(uint4*)&As[(64 + tq) * 32 + tr] = av1;
        *(uint4*)&Bs[tq * 32 + tr]        = bv;
        __syncthreads();

        if (k0 + 32 < K) {
            av0 = *(const uint4*)(Ar0 + k0 + 32);
            av1 = *(const uint4*)(Ar1 + k0 + 32);
            bv  = *(const uint4*)(Br  + k0 + 32);
        }

        f16x8 af[2], bfr[4];
#pragma unroll
        for (int m = 0; m < 2; ++m)
            af[m] = *(const f16x8*)&As[(w * 32 + m * 16 + l15) * 32 + l4 * 8];
#pragma unroll
        for (int n = 0; n < 4; ++n)
            bfr[n] = *(const f16x8*)&Bs[(n * 16 + l15) * 32 + l4 * 8];
#pragma unroll
        for (int m = 0; m < 2; ++m)
#pragma unroll
            for (int n = 0; n < 4; ++n)
                acc[m][n] = __builtin_amdgcn_mfma_f32_16x16x32_f16(
                    af[m], bfr[n], acc[m][n], 0, 0, 0);
    }

#pragma unroll
    for (int n = 0; n < 4; ++n) {
        const int col = n * 16 + l15;
#pragma unroll
        for (int m = 0; m < 2; ++m) {
            const int rowb = row0 + w * 32 + m * 16 + (l4 << 2);
#pragma unroll
            for (int r = 0; r < 4; ++r)
                C[(size_t)(rowb + r) * ldc + col] = acc[m][n][r] * inv;
        }
    }
}

// ---------------- fp32 vector GEMM (input projection, K=64) ----------------
__global__ __launch_bounds__(256) void gemm_in(
    const float* __restrict__ A, int lda,
    const float* __restrict__ B, int ldb,
    const float* __restrict__ bias,
    float* __restrict__ C, int ldc, int K,
    unsigned int* __restrict__ oamax)
{
    __shared__ __align__(16) float As[8][128];
    __shared__ __align__(16) float Bs[8][128];
    const int tid  = threadIdx.x;
    const int row0 = blockIdx.y << 7;
    const int col0 = blockIdx.x << 7;
    const int tx = tid & 15, ty = tid >> 4;

    float acc[8][8];
#pragma unroll
    for (int i = 0; i < 8; ++i)
#pragma unroll
        for (int j = 0; j < 8; ++j) acc[i][j] = 0.f;

    const int arow = tid >> 1;
    const int acol = (tid & 1) << 2;
    const float* Ap = A + (size_t)(row0 + arow) * lda + acol;
    const float* Bp = B + (size_t)(col0 + arow) * ldb + acol;

    for (int k0 = 0; k0 < K; k0 += 8) {
        const float4 av = *(const float4*)(Ap + k0);
        const float4 bv = *(const float4*)(Bp + k0);
        __syncthreads();
        As[acol + 0][arow] = av.x; As[acol + 1][arow] = av.y;
        As[acol + 2][arow] = av.z; As[acol + 3][arow] = av.w;
        Bs[acol + 0][arow] = bv.x; Bs[acol + 1][arow] = bv.y;
        Bs[acol + 2][arow] = bv.z; Bs[acol + 3][arow] = bv.w;
        __syncthreads();
#pragma unroll
        for (int k = 0; k < 8; ++k) {
            float a[8], b[8];
            *(float4*)&a[0] = *(const float4*)&As[k][ty << 3];
            *(float4*)&a[4] = *(const float4*)&As[k][(ty << 3) + 4];
            *(float4*)&b[0] = *(const float4*)&Bs[k][tx << 3];
            *(float4*)&b[4] = *(const float4*)&Bs[k][(tx << 3) + 4];
#pragma unroll
            for (int i = 0; i < 8; ++i)
#pragma unroll
                for (int j = 0; j < 8; ++j)
                    acc[i][j] = fmaf(a[i], b[j], acc[i][j]);
        }
    }

    float bv8[8];
#pragma unroll
    for (int j = 0; j < 8; ++j) bv8[j] = bias[col0 + (tx << 3) + j];

    float am = 0.f;
#pragma unroll
    for (int i = 0; i < 8; ++i) {
        float v[8];
#pragma unroll
        for (int j = 0; j < 8; ++j) {
            v[j] = acc[i][j] + bv8[j];
            am = fmaxf(am, fabsf(v[j]));
        }
        float* Cp = C + (size_t)(row0 + (ty << 3) + i) * ldc + col0 + (tx << 3);
        *(float4*)(Cp)     = make_float4(v[0], v[1], v[2], v[3]);
        *(float4*)(Cp + 4) = make_float4(v[4], v[5], v[6], v[7]);
    }
#pragma unroll
    for (int off = 32; off; off >>= 1) am = fmaxf(am, __shfl_down(am, off));
    if ((tid & 63) == 0) atomicMax(oamax, __float_as_uint(am));
}

// depthwise causal conv (DC=4) + bias + SiLU, float4 in / scaled f16 out.
__global__ __launch_bounds__(256) void conv_silu_kernel(
    const float* __restrict__ xz, const float* __restrict__ cw,
    const float* __restrict__ cb, unsigned short* __restrict__ u,
    size_t total4, const unsigned int* __restrict__ uslot)
{
    const float s = decode_scale(*uslot);
    for (size_t i = (size_t)blockIdx.x * 256 + threadIdx.x; i < total4;
         i += (size_t)gridDim.x * 256) {
        const size_t e = i * 4;
        const int c = (int)(e & (DI_ - 1));
        const size_t m = e >> 10;
        const int t = (int)(m & (T_ - 1));
        const float* xr = xz + m * 2048 + c;
        const float4 zero = make_float4(0.f, 0.f, 0.f, 0.f);
        const float4 x0 = (t >= 3) ? *(const float4*)(xr - 3 * 2048) : zero;
        const float4 x1 = (t >= 2) ? *(const float4*)(xr - 2 * 2048) : zero;
        const float4 x2 = (t >= 1) ? *(const float4*)(xr - 1 * 2048) : zero;
        const float4 x3 = *(const float4*)(xr);
        const float4 cbv = *(const float4*)(cb + c);
        const float4 w0 = *(const float4*)(cw + (size_t)c * 4);
        const float4 w1 = *(const float4*)(cw + (size_t)(c + 1) * 4);
        const float4 w2 = *(const float4*)(cw + (size_t)(c + 2) * 4);
        const float4 w3 = *(const float4*)(cw + (size_t)(c + 3) * 4);
        float4 r;
        r.x = silu_f(fmaf(x3.x, w0.w, fmaf(x2.x, w0.z, fmaf(x1.x, w0.y, fmaf(x0.x, w0.x, cbv.x)))));
        r.y = silu_f(fmaf(x3.y, w1.w, fmaf(x2.y, w1.z, fmaf(x1.y, w1.y, fmaf(x0.y, w1.x, cbv.y)))));
        r.z = silu_f(fmaf(x3.z, w2.w, fmaf(x2.z, w2.z, fmaf(x1.z, w2.y, fmaf(x0.z, w2.x, cbv.z)))));
        r.w = silu_f(fmaf(x3.w, w3.w, fmaf(x2.w, w3.z, fmaf(x1.w, w3.y, fmaf(x0.w, w3.x, cbv.w)))));
        *(ushort4*)(u + e) = make_ushort4(f2h(r.x * s), f2h(r.y * s),
                                          f2h(r.z * s), f2h(r.w * s));
    }
}

// -------- chunk-parallel selective scan, delta fused (3 phases) -----------
// u stored f16 (scale 1/sU applied on load). delta inline from dbc+Wdt.
// Carry state compressed: pass1 stores sdl = Sum(dl); carry reconstructs p.

__device__ __forceinline__ bool geo_check(const float* a2) {
    bool ok = true;
#pragma unroll
    for (int n = 1; n < N_; ++n)
        ok = ok && (fabsf(a2[n] - a2[0] * (n + 1)) <=
                    1e-5f * fmaxf(1.f, fabsf(a2[n])));
    return ok;
}

__global__ __launch_bounds__(256) void scan_pass1(
    const unsigned short* __restrict__ u, const float* __restrict__ dbc,
    const float* __restrict__ A_log_l, const float* __restrict__ Wdt_l,
    const float* __restrict__ bdt_l, const unsigned int* __restrict__ uslot,
    float* __restrict__ SDL, float* __restrict__ S)
{
    __shared__ __align__(16) float sAll[CL_][64];
    const int tid = threadIdx.x;
    const int b = blockIdx.x, ch = blockIdx.z;
    const int d = (blockIdx.y << 8) + tid;

    float a2[N_], hs[N_];
#pragma unroll
    for (int n = 0; n < N_; ++n) {
        a2[n] = -__expf(A_log_l[d * N_ + n]) * 1.44269504f;
        hs[n] = 0.f;
    }
    const bool geo = geo_check(a2);
    const float invU = 1.f / decode_scale(*uslot);
    float wdt[32];
#pragma unroll
    for (int k = 0; k < 32; k += 4)
        *(float4*)&wdt[k] = *(const float4*)(Wdt_l + (size_t)d * 32 + k);
    const float bdt_d = bdt_l[d];

    const size_t base64 = ((size_t)b * T_ + (size_t)ch * CL_) * 64;
    float* sflat = &sAll[0][0];
    for (int i = tid; i < CL_ * 64; i += 256) sflat[i] = dbc[base64 + i];
    __syncthreads();

    float sdl = 0.f;
    if (geo) {
        for (int tt = 0; tt < CL_; ++tt) {
            float t = bdt_d;
#pragma unroll
            for (int k = 0; k < 32; k += 4) {
                const float4 dv = *(const float4*)&sAll[tt][k];
                t = fmaf(dv.x, wdt[k + 0], t);
                t = fmaf(dv.y, wdt[k + 1], t);
                t = fmaf(dv.z, wdt[k + 2], t);
                t = fmaf(dv.w, wdt[k + 3], t);
            }
            const float dl = softplus_f(t);
            sdl += dl;
            const size_t m = (size_t)b * T_ + ch * CL_ + tt;
            const float du = dl * (h2f(u[m * DI_ + d]) * invU);
            const float r = exp2f(dl * a2[0]);
            float dA = r;
#pragma unroll
            for (int n = 0; n < N_; ++n) {
                hs[n] = fmaf(dA, hs[n], du * sAll[tt][32 + n]);
                dA *= r;
            }
        }
    } else {
        for (int tt = 0; tt < CL_; ++tt) {
            float t = bdt_d;
#pragma unroll
            for (int k = 0; k < 32; k += 4) {
                const float4 dv = *(const float4*)&sAll[tt][k];
                t = fmaf(dv.x, wdt[k + 0], t);
                t = fmaf(dv.y, wdt[k + 1], t);
                t = fmaf(dv.z, wdt[k + 2], t);
                t = fmaf(dv.w, wdt[k + 3], t);
            }
            const float dl = softplus_f(t);
            sdl += dl;
            const size_t m = (size_t)b * T_ + ch * CL_ + tt;
            const float du = dl * (h2f(u[m * DI_ + d]) * invU);
#pragma unroll
            for (int n = 0; n < N_; ++n) {
                const float dA = exp2f(dl * a2[n]);
                hs[n] = fmaf(dA, hs[n], du * sAll[tt][32 + n]);
            }
        }
    }
    SDL[(size_t)((b * NCH_ + ch) << 10) + d] = sdl;
#pragma unroll
    for (int n = 0; n < N_; ++n) {
        const size_t idx = (size_t)(((b * NCH_ + ch) * N_ + n) << 10) + d;
        S[idx] = hs[n];
    }
}

// carry: per (b,n,d); p reconstructed from sdl. S[ch] becomes h_init(ch).
__global__ __launch_bounds__(256) void scan_carry(
    const float* __restrict__ SDL, float* __restrict__ S,
    const float* __restrict__ A_log_l)
{
    const size_t gid = (size_t)blockIdx.x * 256 + threadIdx.x;
    const int d = (int)(gid & 1023);
    const int n = (int)((gid >> 10) & 15);
    const int b = (int)(gid >> 14);
    const float a2n = -__expf(A_log_l[d * N_ + n]) * 1.44269504f;
    float hc = 0.f;
    for (int ch = 0; ch < NCH_; ++ch) {
        const float sdl = SDL[(size_t)((b * NCH_ + ch) << 10) + d];
        const float p = exp2f(sdl * a2n);
        const size_t idx = (size_t)(((b * NCH_ + ch) * N_ + n) << 10) + d;
        const float s = S[idx];
        S[idx] = hc;
        hc = fmaf(p, hc, s);
    }
}

__global__ __launch_bounds__(256) void scan_pass3(
    float* __restrict__ xz, const unsigned short* __restrict__ u,
    const float* __restrict__ dbc, const float* __restrict__ A_log_l,
    const float* __restrict__ Wdt_l, const float* __restrict__ bdt_l,
    const float* __restrict__ Dp_l, const unsigned int* __restrict__ uslot,
    const float* __restrict__ S, unsigned int* __restrict__ gmax)
{
    __shared__ __align__(16) float sAll[CL_][64];
    const int tid = threadIdx.x;
    const int b = blockIdx.x, ch = blockIdx.z;
    const int d = (blockIdx.y << 8) + tid;

    float a2[N_], hs[N_];
#pragma unroll
    for (int n = 0; n < N_; ++n) {
        a2[n] = -__expf(A_log_l[d * N_ + n]) * 1.44269504f;
        hs[n] = S[(size_t)(((b * NCH_ + ch) * N_ + n) << 10) + d];
    }
    const bool geo = geo_check(a2);
    const float invU = 1.f / decode_scale(*uslot);
    float wdt[32];
#pragma unroll
    for (int k = 0; k < 32; k += 4)
        *(float4*)&wdt[k] = *(const float4*)(Wdt_l + (size_t)d * 32 + k);
    const float bdt_d = bdt_l[d];
    const float Dpd = Dp_l[d];

    const size_t base64 = ((size_t)b * T_ + (size_t)ch * CL_) * 64;
    float* sflat = &sAll[0][0];
    for (int i = tid; i < CL_ * 64; i += 256) sflat[i] = dbc[base64 + i];
    __syncthreads();

    float gm = 0.f;
    if (geo) {
        for (int tt = 0; tt < CL_; ++tt) {
            float t = bdt_d;
#pragma unroll
            for (int k = 0; k < 32; k += 4) {
                const float4 dv = *(const float4*)&sAll[tt][k];
                t = fmaf(dv.x, wdt[k + 0], t);
                t = fmaf(dv.y, wdt[k + 1], t);
                t = fmaf(dv.z, wdt[k + 2], t);
                t = fmaf(dv.w, wdt[k + 3], t);
            }
            const float dl = softplus_f(t);
            const size_t m = (size_t)b * T_ + ch * CL_ + tt;
            const float uv = h2f(u[m * DI_ + d]) * invU;
            const float du = dl * uv;
            const float r = exp2f(dl * a2[0]);
            float dA = r;
            float yv = 0.f;
#pragma unroll
            for (int n = 0; n < N_; ++n) {
                hs[n] = fmaf(dA, hs[n], du * sAll[tt][32 + n]);
                yv = fmaf(hs[n], sAll[tt][48 + n], yv);
                dA *= r;
            }
            yv = fmaf(uv, Dpd, yv);
            const float g = yv * silu_f(xz[m * 2048 + DI_ + d]);
            xz[m * 2048 + d] = g;
            gm = fmaxf(gm, fabsf(g));
        }
    } else {
        for (int tt = 0; tt < CL_; ++tt) {
            float t = bdt_d;
#pragma unroll
            for (int k = 0; k < 32; k += 4) {
                const float4 dv = *(const float4*)&sAll[tt][k];
                t = fmaf(dv.x, wdt[k + 0], t);
                t = fmaf(dv.y, wdt[k + 1], t);
                t = fmaf(dv.z, wdt[k + 2], t);
                t = fmaf(dv.w, wdt[k + 3], t);
            }
            const float dl = softplus_f(t);
            const size_t m = (size_t)b * T_ + ch * CL_ + tt;
            const float uv = h2f(u[m * DI_ + d]) * invU;
            const float du = dl * uv;
            float yv = 0.f;
#pragma unroll
            for (int n = 0; n < N_; ++n) {
                const float dA = exp2f(dl * a2[n]);
                hs[n] = fmaf(dA, hs[n], du * sAll[tt][32 + n]);
                yv = fmaf(hs[n], sAll[tt][48 + n], yv);
            }
            yv = fmaf(uv, Dpd, yv);
            const float g = yv * silu_f(xz[m * 2048 + DI_ + d]);
            xz[m * 2048 + d] = g;
            gm = fmaxf(gm, fabsf(g));
        }
    }
#pragma unroll
    for (int off = 32; off; off >>= 1) gm = fmaxf(gm, __shfl_down(gm, off));
    if ((tid & 63) == 0) atomicMax(gmax, __float_as_uint(gm));
}

extern "C" void kernel_launch(void* const* d_in, const int* in_sizes, int n_in,
                              void* d_out, int out_size, void* d_ws, size_t ws_size,
                              hipStream_t stream) {
    const float* x     = (const float*)d_in[0];
    const float* Wi    = (const float*)d_in[1];
    const float* bi    = (const float*)d_in[2];
    const float* Win   = (const float*)d_in[3];
    const float* convw = (const float*)d_in[4];
    const float* convb = (const float*)d_in[5];
    const float* Wx    = (const float*)d_in[6];
    const float* Wdt   = (const float*)d_in[7];
    const float* bdt   = (const float*)d_in[8];
    const float* A_log = (const float*)d_in[9];
    const float* Dp    = (const float*)d_in[10];
    const float* Wout  = (const float*)d_in[11];
    const float* Wo    = (const float*)d_in[12];
    const float* bo    = (const float*)d_in[13];
    float* out = (float*)d_out;

    // Per-row f32: xz 2048 + u(f16) 512 + dbc 64 + hPS 512 (h | SDL+S) = 3136.
    // (Keep the proven 3648 budget check for safety margin.)
    const size_t rowf = 3648;
    const size_t wextra =
        (3 * 1048576 + 3 * 524288 + 65536 + 3 * 65536) / 2 + 32;
    int CB = BB_;
    while (CB > 1 && ((size_t)CB * T_ * rowf + wextra) * sizeof(float) > ws_size) CB >>= 1;
    const size_t Mc = (size_t)CB * T_;

    const dim3 blk(256);
    const int rowTiles = (int)(Mc / 128);

    float* ws   = (float*)d_ws;
    float* xz   = ws;                    // Mc*2048 (xin/g | z)
    float* uf   = xz + Mc * 2048;        // Mc*512 f32 = Mc*1024 ushorts (u f16)
    unsigned short* ub = (unsigned short*)uf;
    float* dbc  = uf + Mc * 512;         // Mc*64
    float* hPS  = dbc + Mc * 64;         // Mc*512: h (ld 512) / SDL+S
    float* hb   = hPS;
    float* Sdl  = hPS;                               // Mc*16 floats
    float* Sbuf = hPS + Mc * 16;                     // Mc*256 floats
    unsigned short* WinH  = (unsigned short*)(hPS + Mc * 512);
    unsigned short* WoutH = WinH + 3 * 1048576;
    unsigned short* WoH   = WoutH + 3 * 524288;
    unsigned short* WxH   = WoH + 65536;
    unsigned int* scales  = (unsigned int*)(WxH + 3 * 65536);
    // slots: 0-2 Win, 3-5 Wout, 6 Wo, 7-9 Wx,
    //        10..13 h[0..3], 14-16 g[l], 17-19 (unused), 20-22 ubound[l],
    //        26-28 wb[l] (weight row-sum bound, prep-only)

    hipMemsetAsync(scales, 0, 32 * sizeof(unsigned int), stream);

    amax_all<<<dim3(128, 1, 10), blk, 0, stream>>>(Win, Wout, Wx, Wo, scales);
    winrow_kernel<<<dim3(512, 1, 3), blk, 0, stream>>>(Win, scales);
    cast_all<<<dim3(64, 1, 10), blk, 0, stream>>>(
        Win, Wout, Wx, Wo, WinH, WoutH, WxH, WoH, scales);

    for (int c = 0; c < BB_ / CB; ++c) {
        const float* x_c = x + (size_t)c * Mc * DIN_;
        float* out_c     = out + (size_t)c * Mc * DOUT_;

        hipMemsetAsync(scales + 10, 0, 16 * sizeof(unsigned int), stream);

        // h = x @ Wi.T + bi  (fp32, K=64) -> hb (ld 512), amax -> h[0]
        gemm_in<<<dim3(D_ / 128, rowTiles), blk, 0, stream>>>(
            x_c, DIN_, Wi, DIN_, bi, hb, D_, DIN_, scales + 10);

        for (int l = 0; l < L_; ++l) {
            const float* cw_l   = convw + (size_t)l * DI_ * DC_;
            const float* cb_l   = convb + (size_t)l * DI_;
            const float* Wdt_l  = Wdt  + (size_t)l * DI_ * R_;
            const float* bdt_l  = bdt  + (size_t)l * DI_;
            const float* Alog_l = A_log + (size_t)l * DI_ * N_;
            const float* Dp_l   = Dp   + (size_t)l * DI_;

            // u-scale bound from amax(h)*wb[l] (tiny; overlaps xz GEMM)
            ubound_kernel<<<dim3(1), blk, 0, stream>>>(
                cw_l, cb_l, scales + 10 + l, scales + 26 + l, scales + 20 + l);

            // xz = h @ Win.T  (A fp32 staged-cast, B async-lds; no amax)
            gemm_f32a_t128<0><<<dim3(2048 / 128, rowTiles), blk, 0, stream>>>(
                hb, D_, WinH + (size_t)l * 1048576, D_, nullptr,
                xz, 2048, D_, scales + 10 + l, scales + l, nullptr);

            // u(f16) = silu(causal_dwconv(xin) + cb) * sU
            conv_silu_kernel<<<dim3(2048), blk, 0, stream>>>(
                xz, cw_l, cb_l, ub, Mc * DI_ / 4, scales + 20 + l);

            // dbc = u @ Wx.T  (f16 MFMA 128x64, A pre-scaled f16)
            gemm_f16_t64n<<<dim3(1, rowTiles), blk, 0, stream>>>(
                ub, DI_, WxH + (size_t)l * 65536, DI_, dbc, 64, DI_,
                scales + 20 + l, scales + 7 + l);

            // chunk-parallel scan with fused delta; g -> xz[:, :1024]
            scan_pass1<<<dim3(CB, DI_ / 256, NCH_), blk, 0, stream>>>(
                ub, dbc, Alog_l, Wdt_l, bdt_l, scales + 20 + l, Sdl, Sbuf);
            scan_carry<<<dim3(CB * 64), blk, 0, stream>>>(Sdl, Sbuf, Alog_l);
            scan_pass3<<<dim3(CB, DI_ / 256, NCH_), blk, 0, stream>>>(
                xz, ub, dbc, Alog_l, Wdt_l, bdt_l, Dp_l, scales + 20 + l,
                Sbuf, scales + 14 + l);

            // h = g @ Wout.T  (A fp32 staged-cast) -> hb (SDL/S dead)
            gemm_f32a_t128<0><<<dim3(D_ / 128, rowTiles), blk, 0, stream>>>(
                xz, 2048, WoutH + (size_t)l * 524288, DI_, nullptr,
                hb, D_, DI_, scales + 14 + l, scales + 3 + l, scales + 11 + l);
        }

        // out = tanh(h @ Wo.T + bo)
        gemm_f32a_t128<3><<<dim3(DOUT_ / 128, rowTiles), blk, 0, stream>>>(
            hb, D_, WoH, D_, bo, out_c, DOUT_, D_,
            scales + 13, scales + 6, nullptr);
    }
}

// Round 21
// 2178.119 us; speedup vs baseline: 1.3178x; 1.1855x over previous
//
#include <hip/hip_runtime.h>
#include <hip/hip_bf16.h>

#define BB_ 16
#define T_ 2048
#define DIN_ 64
#define D_ 512
#define DI_ 1024
#define N_ 16
#define DC_ 4
#define R_ 32
#define L_ 3
#define DOUT_ 128
#define CL_ 64               // scan chunk length
#define NCH_ (T_ / CL_)      // 32 chunks

typedef __attribute__((ext_vector_type(8))) _Float16 f16x8;
typedef __attribute__((ext_vector_type(4))) float f32x4;

__device__ __forceinline__ float silu_f(float x) { return x / (1.f + __expf(-x)); }

// fast branch-free softplus: log(1+e^t) = max(t,0) + log(1+e^-|t|)
__device__ __forceinline__ float softplus_f(float t) {
    return fmaxf(t, 0.f) + __logf(1.f + __expf(-fabsf(t)));
}

__device__ __forceinline__ unsigned short f2h(float f) {
    union { _Float16 h; unsigned short u; } c;
    c.h = (_Float16)f;   // RNE
    return c.u;
}

__device__ __forceinline__ float h2f(unsigned short u) {
    union { unsigned short u; _Float16 h; } c;
    c.u = u;
    return (float)c.h;
}

// async global->LDS 16B per lane; LDS dest must be lane-linear (tid*16B).
__device__ __forceinline__ void gload_lds16(const unsigned short* g,
                                            unsigned short* l) {
    __builtin_amdgcn_global_load_lds(
        (const __attribute__((address_space(1))) void*)g,
        (__attribute__((address_space(3))) void*)l, 16, 0, 0);
}

// decode scale from amax bits: s = 2^(11 - e), so s*amax lands in [2^11, 2^12)
__device__ __forceinline__ float decode_scale(unsigned int bits) {
    if (bits == 0u) return 1.f;
    const int E = (int)(bits >> 23) & 0xFF;
    return __uint_as_float((unsigned)(265 - E) << 23);
}

__device__ __forceinline__ uint4 pack8(float4 lo, float4 hi, float s) {
    union { uint4 u; unsigned short h[8]; } r;
    r.h[0] = f2h(lo.x * s); r.h[1] = f2h(lo.y * s);
    r.h[2] = f2h(lo.z * s); r.h[3] = f2h(lo.w * s);
    r.h[4] = f2h(hi.x * s); r.h[5] = f2h(hi.y * s);
    r.h[6] = f2h(hi.z * s); r.h[7] = f2h(hi.w * s);
    return r.u;
}

// regions: 0-2 Win[l] (262144 f4), 3-5 Wout[l] (131072), 6 Wo (16384),
// 7-9 Wx[l] (16384). slot == region.
__device__ __forceinline__ const float* wregion(
    int r, const float* Win, const float* Wout, const float* Wx,
    const float* Wo, size_t* n4)
{
    if (r < 3)       { *n4 = 262144; return Win  + (size_t)r * 1048576; }
    else if (r < 6)  { *n4 = 131072; return Wout + (size_t)(r - 3) * 524288; }
    else if (r == 6) { *n4 = 16384;  return Wo; }
    else             { *n4 = 16384;  return Wx  + (size_t)(r - 7) * 65536; }
}

__global__ __launch_bounds__(256) void amax_all(
    const float* __restrict__ Win, const float* __restrict__ Wout,
    const float* __restrict__ Wx, const float* __restrict__ Wo,
    unsigned int* __restrict__ scales)
{
    size_t n4;
    const float* p = wregion(blockIdx.z, Win, Wout, Wx, Wo, &n4);
    float m = 0.f;
    for (size_t i = (size_t)blockIdx.x * 256 + threadIdx.x; i < n4;
         i += (size_t)gridDim.x * 256) {
        const float4 v = ((const float4*)p)[i];
        m = fmaxf(m, fmaxf(fmaxf(fabsf(v.x), fabsf(v.y)),
                           fmaxf(fabsf(v.z), fabsf(v.w))));
    }
#pragma unroll
    for (int off = 32; off; off >>= 1) m = fmaxf(m, __shfl_down(m, off));
    __shared__ float sm[4];
    if ((threadIdx.x & 63) == 0) sm[threadIdx.x >> 6] = m;
    __syncthreads();
    if (threadIdx.x == 0) {
        const float b = fmaxf(fmaxf(sm[0], sm[1]), fmaxf(sm[2], sm[3]));
        atomicMax(scales + blockIdx.z, __float_as_uint(b));
    }
}

__global__ __launch_bounds__(256) void cast_all(
    const float* __restrict__ Win, const float* __restrict__ Wout,
    const float* __restrict__ Wx, const float* __restrict__ Wo,
    unsigned short* __restrict__ WinH, unsigned short* __restrict__ WoutH,
    unsigned short* __restrict__ WxH, unsigned short* __restrict__ WoH,
    const unsigned int* __restrict__ scales)
{
    const int r = blockIdx.z;
    size_t n4;
    const float* p = wregion(r, Win, Wout, Wx, Wo, &n4);
    unsigned short* o;
    if (r < 3)       o = WinH  + (size_t)r * 1048576;
    else if (r < 6)  o = WoutH + (size_t)(r - 3) * 524288;
    else if (r == 6) o = WoH;
    else             o = WxH   + (size_t)(r - 7) * 65536;
    const float s = decode_scale(scales[r]);
    for (size_t i = (size_t)blockIdx.x * 256 + threadIdx.x; i < n4;
         i += (size_t)gridDim.x * 256) {
        const float4 v = ((const float4*)p)[i];
        ((ushort4*)o)[i] = make_ushort4(f2h(v.x * s), f2h(v.y * s),
                                        f2h(v.z * s), f2h(v.w * s));
    }
}

// weight prep: wb[l] = max_j Sum_k |Win[l][j][k]|  -> scales[26+l].
// grid (512, 1, 3): 4 rows/block, 64 lanes/row, 8 cols/lane.
__global__ __launch_bounds__(256) void winrow_kernel(
    const float* __restrict__ Win, unsigned int* __restrict__ scales)
{
    const int l = blockIdx.z;
    const int row = blockIdx.x * 4 + (threadIdx.x >> 6);
    const int lane = threadIdx.x & 63;
    const float* W = Win + (size_t)l * 2 * DI_ * D_ + (size_t)row * D_ + lane * 8;
    float s = 0.f;
#pragma unroll
    for (int k = 0; k < 8; k += 4) {
        const float4 v = *(const float4*)(W + k);
        s += fabsf(v.x) + fabsf(v.y) + fabsf(v.z) + fabsf(v.w);
    }
#pragma unroll
    for (int off = 32; off; off >>= 1) s += __shfl_down(s, off);
    if (lane == 0) atomicMax(scales + 26 + l, __float_as_uint(s));
}

// tiny: xz bound = amax(h)*wb -> xzbslot; u bound from conv weights -> uslot.
__global__ __launch_bounds__(256) void ubound_kernel(
    const float* __restrict__ cw, const float* __restrict__ cb,
    const unsigned int* __restrict__ hslot,
    const unsigned int* __restrict__ wbslot,
    unsigned int* __restrict__ xzbslot, unsigned int* __restrict__ uslot)
{
    const float xzb = __uint_as_float(*hslot) * __uint_as_float(*wbslot);
    if (threadIdx.x == 0) atomicMax(xzbslot, __float_as_uint(xzb));
    float m = 0.f;
    for (int c = threadIdx.x; c < DI_; c += 256) {
        const float4 w = *(const float4*)(cw + (size_t)c * 4);
        const float sw = fabsf(w.x) + fabsf(w.y) + fabsf(w.z) + fabsf(w.w);
        m = fmaxf(m, fabsf(cb[c]) + sw * xzb);
    }
#pragma unroll
    for (int off = 32; off; off >>= 1) m = fmaxf(m, __shfl_down(m, off));
    __shared__ float sm[4];
    if ((threadIdx.x & 63) == 0) sm[threadIdx.x >> 6] = m;
    __syncthreads();
    if (threadIdx.x == 0) {
        const float b = fmaxf(fmaxf(sm[0], sm[1]), fmaxf(sm[2], sm[3]));
        atomicMax(uslot, __float_as_uint(b));
    }
}

// ------- scaled MFMA GEMM, A fp32 (cast during LDS staging), B f16 --------
// 128x128 tile, BK=32, 4 waves (2x2), per-wave 64x64 = 4x4 frags of 16x16x32.
// A: reg-prefetch pipeline. B: async global_load_lds, double-buffered.
// ACT: 0 = none, 3 = +bias tanh. OUTH: 1 = write f16*sOut, 0 = fp32 (+amax).
// NOTE: C must NOT alias A.
template<int ACT, int OUTH>
__global__ __launch_bounds__(256) void gemm_f32a_t128(
    const float* __restrict__ A, int lda,
    const unsigned short* __restrict__ B, int ldb,
    const float* __restrict__ bias,
    void* __restrict__ Cv, int ldc, int K,
    const unsigned int* __restrict__ sa, const unsigned int* __restrict__ sb,
    const unsigned int* __restrict__ so, unsigned int* __restrict__ oamax)
{
    __shared__ __align__(16) unsigned short As[128 * 32];
    __shared__ __align__(16) unsigned short Bs[2][128 * 32];
    const int tid  = threadIdx.x;
    const int lane = tid & 63;
    const int w    = tid >> 6;
    const int wr   = (w >> 1) << 6;
    const int wc   = (w & 1) << 6;
    const int l15  = lane & 15, l4 = lane >> 4;
    const int row0 = blockIdx.y << 7, col0 = blockIdx.x << 7;
    const int tq   = tid >> 2;
    const int tr   = (tid & 3) << 3;

    const float sA  = decode_scale(*sa);
    const float inv = (1.f / sA) * (1.f / decode_scale(*sb));
    const float sOut = OUTH ? decode_scale(*so) : 1.f;

    const float* Ar0 = A + (size_t)(row0 + tq) * lda + tr;
    const float* Ar1 = A + (size_t)(row0 + 64 + tq) * lda + tr;
    const unsigned short* Br0 = B + (size_t)(col0 + tq) * ldb + tr;
    const unsigned short* Br1 = B + (size_t)(col0 + 64 + tq) * ldb + tr;

    f32x4 acc[4][4];
#pragma unroll
    for (int m = 0; m < 4; ++m)
#pragma unroll
        for (int n = 0; n < 4; ++n) acc[m][n] = (f32x4){0.f, 0.f, 0.f, 0.f};

    float4 a0lo = *(const float4*)(Ar0), a0hi = *(const float4*)(Ar0 + 4);
    float4 a1lo = *(const float4*)(Ar1), a1hi = *(const float4*)(Ar1 + 4);
    gload_lds16(Br0, &Bs[0][tq * 32 + tr]);
    gload_lds16(Br1, &Bs[0][(64 + tq) * 32 + tr]);

    int cur = 0;
    for (int k0 = 0; k0 < K; k0 += 32) {
        __syncthreads();
        *(uint4*)&As[tq * 32 + tr]        = pack8(a0lo, a0hi, sA);
        *(uint4*)&As[(64 + tq) * 32 + tr] = pack8(a1lo, a1hi, sA);
        __syncthreads();

        if (k0 + 32 < K) {
            gload_lds16(Br0 + k0 + 32, &Bs[cur ^ 1][tq * 32 + tr]);
            gload_lds16(Br1 + k0 + 32, &Bs[cur ^ 1][(64 + tq) * 32 + tr]);
            a0lo = *(const float4*)(Ar0 + k0 + 32);
            a0hi = *(const float4*)(Ar0 + k0 + 36);
            a1lo = *(const float4*)(Ar1 + k0 + 32);
            a1hi = *(const float4*)(Ar1 + k0 + 36);
        }

        f16x8 af[4], bfr[4];
#pragma unroll
        for (int m = 0; m < 4; ++m)
            af[m] = *(const f16x8*)&As[(wr + m * 16 + l15) * 32 + l4 * 8];
#pragma unroll
        for (int n = 0; n < 4; ++n)
            bfr[n] = *(const f16x8*)&Bs[cur][(wc + n * 16 + l15) * 32 + l4 * 8];
#pragma unroll
        for (int m = 0; m < 4; ++m)
#pragma unroll
            for (int n = 0; n < 4; ++n)
                acc[m][n] = __builtin_amdgcn_mfma_f32_16x16x32_f16(
                    af[m], bfr[n], acc[m][n], 0, 0, 0);
        cur ^= 1;
    }

    float am = 0.f;
#pragma unroll
    for (int n = 0; n < 4; ++n) {
        const int col = col0 + wc + n * 16 + l15;
        float bc = 0.f;
        if (ACT == 3) bc = bias[col];
#pragma unroll
        for (int m = 0; m < 4; ++m) {
            const int rowb = row0 + wr + m * 16 + (l4 << 2);
#pragma unroll
            for (int r = 0; r < 4; ++r) {
                float v = acc[m][n][r] * inv;
                if (ACT == 3) v = tanhf(v + bc);
                if (OUTH) {
                    ((unsigned short*)Cv)[(size_t)(rowb + r) * ldc + col] =
                        f2h(v * sOut);
                } else {
                    ((float*)Cv)[(size_t)(rowb + r) * ldc + col] = v;
                    am = fmaxf(am, fabsf(v));
                }
            }
        }
    }
    if (!OUTH && oamax) {
#pragma unroll
        for (int off = 32; off; off >>= 1) am = fmaxf(am, __shfl_down(am, off));
        if (lane == 0) atomicMax(oamax, __float_as_uint(am));
    }
}

// ---- dbc GEMM: A f16 u (already scaled), B f16 Wx. 128x64 tile, pipelined.
__global__ __launch_bounds__(256) void gemm_f16_t64n(
    const unsigned short* __restrict__ A, int lda,
    const unsigned short* __restrict__ B, int ldb,
    float* __restrict__ C, int ldc, int K,
    const unsigned int* __restrict__ sa, const unsigned int* __restrict__ sb)
{
    __shared__ __align__(16) unsigned short As[128 * 32];
    __shared__ __align__(16) unsigned short Bs[64 * 32];
    const int tid  = threadIdx.x;
    const int lane = tid & 63;
    const int w    = tid >> 6;
    const int l15  = lane & 15, l4 = lane >> 4;
    const int row0 = blockIdx.y << 7;
    const int tq   = tid >> 2;
    const int tr   = (tid & 3) << 3;

    const float inv = (1.f / decode_scale(*sa)) * (1.f / decode_scale(*sb));

    const unsigned short* Ar0 = A + (size_t)(row0 + tq) * lda + tr;
    const unsigned short* Ar1 = A + (size_t)(row0 + 64 + tq) * lda + tr;
    const unsigned short* Br  = B + (size_t)tq * ldb + tr;   // 64 rows

    f32x4 acc[2][4];
#pragma unroll
    for (int m = 0; m < 2; ++m)
#pragma unroll
        for (int n = 0; n < 4; ++n) acc[m][n] = (f32x4){0.f, 0.f, 0.f, 0.f};

    uint4 av0 = *(const uint4*)(Ar0);
    uint4 av1 = *(const uint4*)(Ar1);
    uint4 bv  = *(const uint4*)(Br);

    for (int k0 = 0; k0 < K; k0 += 32) {
        __syncthreads();
        *(uint4*)&As[tq * 32 + tr]        = av0;
        *(uint4*)&As[(64 + tq) * 32 + tr] = av1;
        *(uint4*)&Bs[tq * 32 + tr]        = bv;
        __syncthreads();

        if (k0 + 32 < K) {
            av0 = *(const uint4*)(Ar0 + k0 + 32);
            av1 = *(const uint4*)(Ar1 + k0 + 32);
            bv  = *(const uint4*)(Br  + k0 + 32);
        }

        f16x8 af[2], bfr[4];
#pragma unroll
        for (int m = 0; m < 2; ++m)
            af[m] = *(const f16x8*)&As[(w * 32 + m * 16 + l15) * 32 + l4 * 8];
#pragma unroll
        for (int n = 0; n < 4; ++n)
            bfr[n] = *(const f16x8*)&Bs[(n * 16 + l15) * 32 + l4 * 8];
#pragma unroll
        for (int m = 0; m < 2; ++m)
#pragma unroll
            for (int n = 0; n < 4; ++n)
                acc[m][n] = __builtin_amdgcn_mfma_f32_16x16x32_f16(
                    af[m], bfr[n], acc[m][n], 0, 0, 0);
    }

#pragma unroll
    for (int n = 0; n < 4; ++n) {
        const int col = n * 16 + l15;
#pragma unroll
        for (int m = 0; m < 2; ++m) {
            const int rowb = row0 + w * 32 + m * 16 + (l4 << 2);
#pragma unroll
            for (int r = 0; r < 4; ++r)
                C[(size_t)(rowb + r) * ldc + col] = acc[m][n][r] * inv;
        }
    }
}

// ---------------- fp32 vector GEMM (input projection, K=64) ----------------
__global__ __launch_bounds__(256) void gemm_in(
    const float* __restrict__ A, int lda,
    const float* __restrict__ B, int ldb,
    const float* __restrict__ bias,
    float* __restrict__ C, int ldc, int K,
    unsigned int* __restrict__ oamax)
{
    __shared__ __align__(16) float As[8][128];
    __shared__ __align__(16) float Bs[8][128];
    const int tid  = threadIdx.x;
    const int row0 = blockIdx.y << 7;
    const int col0 = blockIdx.x << 7;
    const int tx = tid & 15, ty = tid >> 4;

    float acc[8][8];
#pragma unroll
    for (int i = 0; i < 8; ++i)
#pragma unroll
        for (int j = 0; j < 8; ++j) acc[i][j] = 0.f;

    const int arow = tid >> 1;
    const int acol = (tid & 1) << 2;
    const float* Ap = A + (size_t)(row0 + arow) * lda + acol;
    const float* Bp = B + (size_t)(col0 + arow) * ldb + acol;

    for (int k0 = 0; k0 < K; k0 += 8) {
        const float4 av = *(const float4*)(Ap + k0);
        const float4 bv = *(const float4*)(Bp + k0);
        __syncthreads();
        As[acol + 0][arow] = av.x; As[acol + 1][arow] = av.y;
        As[acol + 2][arow] = av.z; As[acol + 3][arow] = av.w;
        Bs[acol + 0][arow] = bv.x; Bs[acol + 1][arow] = bv.y;
        Bs[acol + 2][arow] = bv.z; Bs[acol + 3][arow] = bv.w;
        __syncthreads();
#pragma unroll
        for (int k = 0; k < 8; ++k) {
            float a[8], b[8];
            *(float4*)&a[0] = *(const float4*)&As[k][ty << 3];
            *(float4*)&a[4] = *(const float4*)&As[k][(ty << 3) + 4];
            *(float4*)&b[0] = *(const float4*)&Bs[k][tx << 3];
            *(float4*)&b[4] = *(const float4*)&Bs[k][(tx << 3) + 4];
#pragma unroll
            for (int i = 0; i < 8; ++i)
#pragma unroll
                for (int j = 0; j < 8; ++j)
                    acc[i][j] = fmaf(a[i], b[j], acc[i][j]);
        }
    }

    float bv8[8];
#pragma unroll
    for (int j = 0; j < 8; ++j) bv8[j] = bias[col0 + (tx << 3) + j];

    float am = 0.f;
#pragma unroll
    for (int i = 0; i < 8; ++i) {
        float v[8];
#pragma unroll
        for (int j = 0; j < 8; ++j) {
            v[j] = acc[i][j] + bv8[j];
            am = fmaxf(am, fabsf(v[j]));
        }
        float* Cp = C + (size_t)(row0 + (ty << 3) + i) * ldc + col0 + (tx << 3);
        *(float4*)(Cp)     = make_float4(v[0], v[1], v[2], v[3]);
        *(float4*)(Cp + 4) = make_float4(v[4], v[5], v[6], v[7]);
    }
#pragma unroll
    for (int off = 32; off; off >>= 1) am = fmaxf(am, __shfl_down(am, off));
    if ((tid & 63) == 0) atomicMax(oamax, __float_as_uint(am));
}

// depthwise causal conv (DC=4) + bias + SiLU; f16 xz in, scaled f16 u out.
__global__ __launch_bounds__(256) void conv_silu_kernel(
    const unsigned short* __restrict__ xzh, const float* __restrict__ cw,
    const float* __restrict__ cb, unsigned short* __restrict__ u,
    size_t total4, const unsigned int* __restrict__ xzbslot,
    const unsigned int* __restrict__ uslot)
{
    const float invX = 1.f / decode_scale(*xzbslot);
    const float s = decode_scale(*uslot);
    for (size_t i = (size_t)blockIdx.x * 256 + threadIdx.x; i < total4;
         i += (size_t)gridDim.x * 256) {
        const size_t e = i * 4;
        const int c = (int)(e & (DI_ - 1));
        const size_t m = e >> 10;
        const int t = (int)(m & (T_ - 1));
        const unsigned short* xr = xzh + m * 2048 + c;
        float x[4][4];
#pragma unroll
        for (int k = 0; k < 4; ++k) {
            const int dt = 3 - k;
            if (t >= dt) {
                const ushort4 xv = *(const ushort4*)(xr - (size_t)dt * 2048);
                x[k][0] = h2f(xv.x) * invX; x[k][1] = h2f(xv.y) * invX;
                x[k][2] = h2f(xv.z) * invX; x[k][3] = h2f(xv.w) * invX;
            } else {
                x[k][0] = x[k][1] = x[k][2] = x[k][3] = 0.f;
            }
        }
        const float4 cbv = *(const float4*)(cb + c);
        ushort4 o;
        {
            const float4 w = *(const float4*)(cw + (size_t)c * 4);
            o.x = f2h(silu_f(fmaf(x[3][0], w.w, fmaf(x[2][0], w.z,
                     fmaf(x[1][0], w.y, fmaf(x[0][0], w.x, cbv.x))))) * s);
        }
        {
            const float4 w = *(const float4*)(cw + (size_t)(c + 1) * 4);
            o.y = f2h(silu_f(fmaf(x[3][1], w.w, fmaf(x[2][1], w.z,
                     fmaf(x[1][1], w.y, fmaf(x[0][1], w.x, cbv.y))))) * s);
        }
        {
            const float4 w = *(const float4*)(cw + (size_t)(c + 2) * 4);
            o.z = f2h(silu_f(fmaf(x[3][2], w.w, fmaf(x[2][2], w.z,
                     fmaf(x[1][2], w.y, fmaf(x[0][2], w.x, cbv.z))))) * s);
        }
        {
            const float4 w = *(const float4*)(cw + (size_t)(c + 3) * 4);
            o.w = f2h(silu_f(fmaf(x[3][3], w.w, fmaf(x[2][3], w.z,
                     fmaf(x[1][3], w.y, fmaf(x[0][3], w.x, cbv.w))))) * s);
        }
        *(ushort4*)(u + e) = o;
    }
}

// -------- chunk-parallel selective scan, delta fused (3 phases) -----------
// u, z stored f16 (unscaled on load). delta inline from dbc+Wdt.
// Carry state compressed: pass1 stores sdl = Sum(dl); carry reconstructs p.

__device__ __forceinline__ bool geo_check(const float* a2) {
    bool ok = true;
#pragma unroll
    for (int n = 1; n < N_; ++n)
        ok = ok && (fabsf(a2[n] - a2[0] * (n + 1)) <=
                    1e-5f * fmaxf(1.f, fabsf(a2[n])));
    return ok;
}

__global__ __launch_bounds__(256) void scan_pass1(
    const unsigned short* __restrict__ u, const float* __restrict__ dbc,
    const float* __restrict__ A_log_l, const float* __restrict__ Wdt_l,
    const float* __restrict__ bdt_l, const unsigned int* __restrict__ uslot,
    float* __restrict__ SDL, float* __restrict__ S)
{
    __shared__ __align__(16) float sAll[CL_][64];
    const int tid = threadIdx.x;
    const int b = blockIdx.x, ch = blockIdx.z;
    const int d = (blockIdx.y << 8) + tid;

    float a2[N_], hs[N_];
#pragma unroll
    for (int n = 0; n < N_; ++n) {
        a2[n] = -__expf(A_log_l[d * N_ + n]) * 1.44269504f;
        hs[n] = 0.f;
    }
    const bool geo = geo_check(a2);
    const float invU = 1.f / decode_scale(*uslot);
    float wdt[32];
#pragma unroll
    for (int k = 0; k < 32; k += 4)
        *(float4*)&wdt[k] = *(const float4*)(Wdt_l + (size_t)d * 32 + k);
    const float bdt_d = bdt_l[d];

    const size_t base64 = ((size_t)b * T_ + (size_t)ch * CL_) * 64;
    float* sflat = &sAll[0][0];
    for (int i = tid; i < CL_ * 64; i += 256) sflat[i] = dbc[base64 + i];
    __syncthreads();

    float sdl = 0.f;
    if (geo) {
        for (int tt = 0; tt < CL_; ++tt) {
            float t = bdt_d;
#pragma unroll
            for (int k = 0; k < 32; k += 4) {
                const float4 dv = *(const float4*)&sAll[tt][k];
                t = fmaf(dv.x, wdt[k + 0], t);
                t = fmaf(dv.y, wdt[k + 1], t);
                t = fmaf(dv.z, wdt[k + 2], t);
                t = fmaf(dv.w, wdt[k + 3], t);
            }
            const float dl = softplus_f(t);
            sdl += dl;
            const size_t m = (size_t)b * T_ + ch * CL_ + tt;
            const float du = dl * (h2f(u[m * DI_ + d]) * invU);
            const float r = exp2f(dl * a2[0]);
            float dA = r;
#pragma unroll
            for (int n = 0; n < N_; ++n) {
                hs[n] = fmaf(dA, hs[n], du * sAll[tt][32 + n]);
                dA *= r;
            }
        }
    } else {
        for (int tt = 0; tt < CL_; ++tt) {
            float t = bdt_d;
#pragma unroll
            for (int k = 0; k < 32; k += 4) {
                const float4 dv = *(const float4*)&sAll[tt][k];
                t = fmaf(dv.x, wdt[k + 0], t);
                t = fmaf(dv.y, wdt[k + 1], t);
                t = fmaf(dv.z, wdt[k + 2], t);
                t = fmaf(dv.w, wdt[k + 3], t);
            }
            const float dl = softplus_f(t);
            sdl += dl;
            const size_t m = (size_t)b * T_ + ch * CL_ + tt;
            const float du = dl * (h2f(u[m * DI_ + d]) * invU);
#pragma unroll
            for (int n = 0; n < N_; ++n) {
                const float dA = exp2f(dl * a2[n]);
                hs[n] = fmaf(dA, hs[n], du * sAll[tt][32 + n]);
            }
        }
    }
    SDL[(size_t)((b * NCH_ + ch) << 10) + d] = sdl;
#pragma unroll
    for (int n = 0; n < N_; ++n) {
        const size_t idx = (size_t)(((b * NCH_ + ch) * N_ + n) << 10) + d;
        S[idx] = hs[n];
    }
}

// carry: per (b,n,d); p reconstructed from sdl. S[ch] becomes h_init(ch).
__global__ __launch_bounds__(256) void scan_carry(
    const float* __restrict__ SDL, float* __restrict__ S,
    const float* __restrict__ A_log_l)
{
    const size_t gid = (size_t)blockIdx.x * 256 + threadIdx.x;
    const int d = (int)(gid & 1023);
    const int n = (int)((gid >> 10) & 15);
    const int b = (int)(gid >> 14);
    const float a2n = -__expf(A_log_l[d * N_ + n]) * 1.44269504f;
    float hc = 0.f;
    for (int ch = 0; ch < NCH_; ++ch) {
        const float sdl = SDL[(size_t)((b * NCH_ + ch) << 10) + d];
        const float p = exp2f(sdl * a2n);
        const size_t idx = (size_t)(((b * NCH_ + ch) * N_ + n) << 10) + d;
        const float s = S[idx];
        S[idx] = hc;
        hc = fmaf(p, hc, s);
    }
}

__global__ __launch_bounds__(256) void scan_pass3(
    const unsigned short* __restrict__ xzh, float* __restrict__ g,
    const unsigned short* __restrict__ u, const float* __restrict__ dbc,
    const float* __restrict__ A_log_l, const float* __restrict__ Wdt_l,
    const float* __restrict__ bdt_l, const float* __restrict__ Dp_l,
    const unsigned int* __restrict__ xzbslot,
    const unsigned int* __restrict__ uslot,
    const float* __restrict__ S, unsigned int* __restrict__ gmax)
{
    __shared__ __align__(16) float sAll[CL_][64];
    const int tid = threadIdx.x;
    const int b = blockIdx.x, ch = blockIdx.z;
    const int d = (blockIdx.y << 8) + tid;

    float a2[N_], hs[N_];
#pragma unroll
    for (int n = 0; n < N_; ++n) {
        a2[n] = -__expf(A_log_l[d * N_ + n]) * 1.44269504f;
        hs[n] = S[(size_t)(((b * NCH_ + ch) * N_ + n) << 10) + d];
    }
    const bool geo = geo_check(a2);
    const float invX = 1.f / decode_scale(*xzbslot);
    const float invU = 1.f / decode_scale(*uslot);
    float wdt[32];
#pragma unroll
    for (int k = 0; k < 32; k += 4)
        *(float4*)&wdt[k] = *(const float4*)(Wdt_l + (size_t)d * 32 + k);
    const float bdt_d = bdt_l[d];
    const float Dpd = Dp_l[d];

    const size_t base64 = ((size_t)b * T_ + (size_t)ch * CL_) * 64;
    float* sflat = &sAll[0][0];
    for (int i = tid; i < CL_ * 64; i += 256) sflat[i] = dbc[base64 + i];
    __syncthreads();

    float gm = 0.f;
    if (geo) {
        for (int tt = 0; tt < CL_; ++tt) {
            float t = bdt_d;
#pragma unroll
            for (int k = 0; k < 32; k += 4) {
                const float4 dv = *(const float4*)&sAll[tt][k];
                t = fmaf(dv.x, wdt[k + 0], t);
                t = fmaf(dv.y, wdt[k + 1], t);
                t = fmaf(dv.z, wdt[k + 2], t);
                t = fmaf(dv.w, wdt[k + 3], t);
            }
            const float dl = softplus_f(t);
            const size_t m = (size_t)b * T_ + ch * CL_ + tt;
            const float uv = h2f(u[m * DI_ + d]) * invU;
            const float du = dl * uv;
            const float r = exp2f(dl * a2[0]);
            float dA = r;
            float yv = 0.f;
#pragma unroll
            for (int n = 0; n < N_; ++n) {
                hs[n] = fmaf(dA, hs[n], du * sAll[tt][32 + n]);
                yv = fmaf(hs[n], sAll[tt][48 + n], yv);
                dA *= r;
            }
            yv = fmaf(uv, Dpd, yv);
            const float zv = h2f(xzh[m * 2048 + DI_ + d]) * invX;
            const float gv = yv * silu_f(zv);
            g[m * DI_ + d] = gv;
            gm = fmaxf(gm, fabsf(gv));
        }
    } else {
        for (int tt = 0; tt < CL_; ++tt) {
            float t = bdt_d;
#pragma unroll
            for (int k = 0; k < 32; k += 4) {
                const float4 dv = *(const float4*)&sAll[tt][k];
                t = fmaf(dv.x, wdt[k + 0], t);
                t = fmaf(dv.y, wdt[k + 1], t);
                t = fmaf(dv.z, wdt[k + 2], t);
                t = fmaf(dv.w, wdt[k + 3], t);
            }
            const float dl = softplus_f(t);
            const size_t m = (size_t)b * T_ + ch * CL_ + tt;
            const float uv = h2f(u[m * DI_ + d]) * invU;
            const float du = dl * uv;
            float yv = 0.f;
#pragma unroll
            for (int n = 0; n < N_; ++n) {
                const float dA = exp2f(dl * a2[n]);
                hs[n] = fmaf(dA, hs[n], du * sAll[tt][32 + n]);
                yv = fmaf(hs[n], sAll[tt][48 + n], yv);
            }
            yv = fmaf(uv, Dpd, yv);
            const float zv = h2f(xzh[m * 2048 + DI_ + d]) * invX;
            const float gv = yv * silu_f(zv);
            g[m * DI_ + d] = gv;
            gm = fmaxf(gm, fabsf(gv));
        }
    }
#pragma unroll
    for (int off = 32; off; off >>= 1) gm = fmaxf(gm, __shfl_down(gm, off));
    if ((tid & 63) == 0) atomicMax(gmax, __float_as_uint(gm));
}

extern "C" void kernel_launch(void* const* d_in, const int* in_sizes, int n_in,
                              void* d_out, int out_size, void* d_ws, size_t ws_size,
                              hipStream_t stream) {
    const float* x     = (const float*)d_in[0];
    const float* Wi    = (const float*)d_in[1];
    const float* bi    = (const float*)d_in[2];
    const float* Win   = (const float*)d_in[3];
    const float* convw = (const float*)d_in[4];
    const float* convb = (const float*)d_in[5];
    const float* Wx    = (const float*)d_in[6];
    const float* Wdt   = (const float*)d_in[7];
    const float* bdt   = (const float*)d_in[8];
    const float* A_log = (const float*)d_in[9];
    const float* Dp    = (const float*)d_in[10];
    const float* Wout  = (const float*)d_in[11];
    const float* Wo    = (const float*)d_in[12];
    const float* bo    = (const float*)d_in[13];
    float* out = (float*)d_out;

    // Per-row f32: xzh(f16) 1024 + g 1024 + u(f16) 512 + dbc 64 + hPS 512
    // = 3136. Keep the proven 3648 budget check for margin.
    const size_t rowf = 3648;
    const size_t wextra =
        (3 * 1048576 + 3 * 524288 + 65536 + 3 * 65536) / 2 + 32;
    int CB = BB_;
    while (CB > 1 && ((size_t)CB * T_ * rowf + wextra) * sizeof(float) > ws_size) CB >>= 1;
    const size_t Mc = (size_t)CB * T_;

    const dim3 blk(256);
    const int rowTiles = (int)(Mc / 128);

    float* ws   = (float*)d_ws;
    unsigned short* xzh = (unsigned short*)ws;       // Mc*2048 ushorts (f16)
    float* gbuf = ws + Mc * 1024;                    // Mc*1024 f32
    unsigned short* ub = (unsigned short*)(gbuf + Mc * 1024); // Mc*1024 ushorts
    float* dbc  = gbuf + Mc * 1024 + Mc * 512;       // Mc*64
    float* hPS  = dbc + Mc * 64;                     // Mc*512: h / SDL+S
    float* hb   = hPS;
    float* Sdl  = hPS;                               // Mc*16 floats
    float* Sbuf = hPS + Mc * 16;                     // Mc*256 floats
    unsigned short* WinH  = (unsigned short*)(hPS + Mc * 512);
    unsigned short* WoutH = WinH + 3 * 1048576;
    unsigned short* WoH   = WoutH + 3 * 524288;
    unsigned short* WxH   = WoH + 65536;
    unsigned int* scales  = (unsigned int*)(WxH + 3 * 65536);
    // slots: 0-2 Win, 3-5 Wout, 6 Wo, 7-9 Wx,
    //        10..13 h[0..3], 14-16 g[l], 17-19 xzb[l], 20-22 ub[l],
    //        26-28 wb[l] (weight row-sum bound, prep-only)

    hipMemsetAsync(scales, 0, 32 * sizeof(unsigned int), stream);

    amax_all<<<dim3(128, 1, 10), blk, 0, stream>>>(Win, Wout, Wx, Wo, scales);
    winrow_kernel<<<dim3(512, 1, 3), blk, 0, stream>>>(Win, scales);
    cast_all<<<dim3(64, 1, 10), blk, 0, stream>>>(
        Win, Wout, Wx, Wo, WinH, WoutH, WxH, WoH, scales);

    for (int c = 0; c < BB_ / CB; ++c) {
        const float* x_c = x + (size_t)c * Mc * DIN_;
        float* out_c     = out + (size_t)c * Mc * DOUT_;

        hipMemsetAsync(scales + 10, 0, 16 * sizeof(unsigned int), stream);

        // h = x @ Wi.T + bi  (fp32, K=64) -> hb (ld 512), amax -> h[0]
        gemm_in<<<dim3(D_ / 128, rowTiles), blk, 0, stream>>>(
            x_c, DIN_, Wi, DIN_, bi, hb, D_, DIN_, scales + 10);

        for (int l = 0; l < L_; ++l) {
            const float* cw_l   = convw + (size_t)l * DI_ * DC_;
            const float* cb_l   = convb + (size_t)l * DI_;
            const float* Wdt_l  = Wdt  + (size_t)l * DI_ * R_;
            const float* bdt_l  = bdt  + (size_t)l * DI_;
            const float* Alog_l = A_log + (size_t)l * DI_ * N_;
            const float* Dp_l   = Dp   + (size_t)l * DI_;

            // xz bound + u bound (tiny; overlaps nothing critical)
            ubound_kernel<<<dim3(1), blk, 0, stream>>>(
                cw_l, cb_l, scales + 10 + l, scales + 26 + l,
                scales + 17 + l, scales + 20 + l);

            // xz(f16) = h @ Win.T  (A fp32 staged-cast, B async-lds)
            gemm_f32a_t128<0, 1><<<dim3(2048 / 128, rowTiles), blk, 0, stream>>>(
                hb, D_, WinH + (size_t)l * 1048576, D_, nullptr,
                xzh, 2048, D_, scales + 10 + l, scales + l,
                scales + 17 + l, nullptr);

            // u(f16) = silu(causal_dwconv(xin) + cb) * sU
            conv_silu_kernel<<<dim3(2048), blk, 0, stream>>>(
                xzh, cw_l, cb_l, ub, Mc * DI_ / 4,
                scales + 17 + l, scales + 20 + l);

            // dbc = u @ Wx.T  (f16 MFMA 128x64, A pre-scaled f16)
            gemm_f16_t64n<<<dim3(1, rowTiles), blk, 0, stream>>>(
                ub, DI_, WxH + (size_t)l * 65536, DI_, dbc, 64, DI_,
                scales + 20 + l, scales + 7 + l);

            // chunk-parallel scan with fused delta; g -> gbuf (fp32)
            scan_pass1<<<dim3(CB, DI_ / 256, NCH_), blk, 0, stream>>>(
                ub, dbc, Alog_l, Wdt_l, bdt_l, scales + 20 + l, Sdl, Sbuf);
            scan_carry<<<dim3(CB * 64), blk, 0, stream>>>(Sdl, Sbuf, Alog_l);
            scan_pass3<<<dim3(CB, DI_ / 256, NCH_), blk, 0, stream>>>(
                xzh, gbuf, ub, dbc, Alog_l, Wdt_l, bdt_l, Dp_l,
                scales + 17 + l, scales + 20 + l, Sbuf, scales + 14 + l);

            // h = g @ Wout.T  (A fp32 contiguous staged-cast) -> hb
            gemm_f32a_t128<0, 0><<<dim3(D_ / 128, rowTiles), blk, 0, stream>>>(
                gbuf, DI_, WoutH + (size_t)l * 524288, DI_, nullptr,
                hb, D_, DI_, scales + 14 + l, scales + 3 + l,
                nullptr, scales + 11 + l);
        }

        // out = tanh(h @ Wo.T + bo)
        gemm_f32a_t128<3, 0><<<dim3(DOUT_ / 128, rowTiles), blk, 0, stream>>>(
            hb, D_, WoH, D_, bo, out_c, DOUT_, D_,
            scales + 13, scales + 6, nullptr, nullptr);
    }
}